// Round 1
// baseline (917.187 us; speedup 1.0000x reference)
//
#include <hip/hip_runtime.h>
#include <hip/hip_bf16.h>

#define DM 2048
#define NTOK 8192
#define EPS 1e-6f

typedef __attribute__((ext_vector_type(8))) short short8;
typedef __attribute__((ext_vector_type(4))) short short4v;
typedef __attribute__((ext_vector_type(4))) float f32x4;
typedef __attribute__((ext_vector_type(16))) float f32x16;

typedef const __attribute__((address_space(1))) void gvoid;
typedef __attribute__((address_space(3))) void lvoid;

static __device__ __forceinline__ unsigned short f2bf(float f) {
    unsigned u = __builtin_bit_cast(unsigned, f);
    unsigned r = u + 0x7FFFu + ((u >> 16) & 1u);
    return (unsigned short)(r >> 16);
}

// ---------------- row norm: alpha*(x-mu)/(std+eps)+beta, std ddof=1, f32 in -> bf16 out
__global__ __launch_bounds__(256) void norm_rows(
        const float* __restrict__ in, const float* __restrict__ alpha,
        const float* __restrict__ beta, unsigned short* __restrict__ out) {
    const int row = blockIdx.x;
    const int t = threadIdx.x;
    const float* x = in + (size_t)row * DM + t * 8;
    float4 v0 = *(const float4*)(x);
    float4 v1 = *(const float4*)(x + 4);
    float s = (v0.x + v0.y) + (v0.z + v0.w) + (v1.x + v1.y) + (v1.z + v1.w);
    float ss = v0.x*v0.x + v0.y*v0.y + v0.z*v0.z + v0.w*v0.w
             + v1.x*v1.x + v1.y*v1.y + v1.z*v1.z + v1.w*v1.w;
    #pragma unroll
    for (int m = 1; m < 64; m <<= 1) {
        s  += __shfl_xor(s, m);
        ss += __shfl_xor(ss, m);
    }
    __shared__ float red[8];
    const int wv = t >> 6, ln = t & 63;
    if (ln == 0) { red[wv] = s; red[4 + wv] = ss; }
    __syncthreads();
    s  = (red[0] + red[1]) + (red[2] + red[3]);
    ss = (red[4] + red[5]) + (red[6] + red[7]);
    const float mu = s * (1.0f / DM);
    float var = (ss - s * mu) * (1.0f / (DM - 1));
    var = fmaxf(var, 0.0f);
    const float scale = 1.0f / (sqrtf(var) + EPS);
    float4 a0 = *(const float4*)(alpha + t*8);
    float4 a1 = *(const float4*)(alpha + t*8 + 4);
    float4 b0 = *(const float4*)(beta + t*8);
    float4 b1 = *(const float4*)(beta + t*8 + 4);
    short8 o;
    o[0] = (short)f2bf(a0.x * (v0.x - mu) * scale + b0.x);
    o[1] = (short)f2bf(a0.y * (v0.y - mu) * scale + b0.y);
    o[2] = (short)f2bf(a0.z * (v0.z - mu) * scale + b0.z);
    o[3] = (short)f2bf(a0.w * (v0.w - mu) * scale + b0.w);
    o[4] = (short)f2bf(a1.x * (v1.x - mu) * scale + b1.x);
    o[5] = (short)f2bf(a1.y * (v1.y - mu) * scale + b1.y);
    o[6] = (short)f2bf(a1.z * (v1.z - mu) * scale + b1.z);
    o[7] = (short)f2bf(a1.w * (v1.w - mu) * scale + b1.w);
    *(short8*)(out + (size_t)row * DM + t * 8) = o;
}

// ---------------- weight transpose+cast: Wt[pc][k] = bf16(W[k][c]); perm: pc=(c&127)*16+(c>>7)
__global__ __launch_bounds__(256) void wtrans(
        const float* __restrict__ W, unsigned short* __restrict__ Wt, int perm) {
    __shared__ float tile[32][33];
    const int bc = blockIdx.x * 32, bk = blockIdx.y * 32;
    const int t = threadIdx.x;
    const int tc = t & 31, tr = t >> 5;
    #pragma unroll
    for (int i = 0; i < 4; ++i)
        tile[tr + i*8][tc] = W[(size_t)(bk + tr + i*8) * DM + bc + tc];
    __syncthreads();
    #pragma unroll
    for (int i = 0; i < 4; ++i) {
        const int c = bc + tr + i*8;
        const int pc = perm ? ((c & 127) * 16 + (c >> 7)) : c;
        Wt[(size_t)pc * DM + bk + tc] = f2bf(tile[tc][tr + i*8]);
    }
}

// ---------------- GEMM: C[M,N] = A(bf16,[M][K]) @ Bt(bf16,[N][K])^T + bias (+resid) (+relu)
// EPI 0: bf16 out w/ bias. EPI 1: bf16 out w/ bias+relu. EPI 2: f32 out w/ bias+resid.
template<int EPI>
__global__ __launch_bounds__(256) void gemm_bt(
        const unsigned short* __restrict__ A, const unsigned short* __restrict__ Bt,
        const float* __restrict__ bias, const float* __restrict__ resid,
        float* __restrict__ outF, unsigned short* __restrict__ outB,
        int M, int N, int K, int biasPerm) {
    __shared__ __align__(16) unsigned short As[128 * 64];
    __shared__ __align__(16) unsigned short Bs[128 * 64];
    const int m0 = blockIdx.y * 128, n0 = blockIdx.x * 128;
    const int t = threadIdx.x, w = t >> 6, l = t & 63;
    const int wr = (w >> 1) * 64, wc = (w & 1) * 64;
    f32x4 acc[4][4] = {};
    const int kTiles = K >> 6;
    const int off0 = w * 4096 + l * 16;
    for (int kt = 0; kt < kTiles; ++kt) {
        const size_t kb = (size_t)kt * 64;
        #pragma unroll
        for (int i = 0; i < 4; ++i) {
            const int off = off0 + i * 1024;
            const int row = off >> 7;
            const int col = (off & 127) >> 1;
            __builtin_amdgcn_global_load_lds(
                (gvoid*)(A + (size_t)(m0 + row) * K + kb + col),
                (lvoid*)((char*)As + w * 4096 + i * 1024), 16, 0, 0);
            __builtin_amdgcn_global_load_lds(
                (gvoid*)(Bt + (size_t)(n0 + row) * K + kb + col),
                (lvoid*)((char*)Bs + w * 4096 + i * 1024), 16, 0, 0);
        }
        __syncthreads();
        #pragma unroll
        for (int ks = 0; ks < 2; ++ks) {
            short8 af[4], bfr[4];
            #pragma unroll
            for (int i = 0; i < 4; ++i) {
                af[i]  = *(const short8*)(As + (wr + i*16 + (l & 15)) * 64 + ks*32 + (l >> 4) * 8);
                bfr[i] = *(const short8*)(Bs + (wc + i*16 + (l & 15)) * 64 + ks*32 + (l >> 4) * 8);
            }
            #pragma unroll
            for (int mi = 0; mi < 4; ++mi)
                #pragma unroll
                for (int ni = 0; ni < 4; ++ni)
                    acc[mi][ni] = __builtin_amdgcn_mfma_f32_16x16x32_bf16(
                        af[mi], bfr[ni], acc[mi][ni], 0, 0, 0);
        }
        __syncthreads();
    }
    #pragma unroll
    for (int ni = 0; ni < 4; ++ni) {
        const int col = n0 + wc + ni*16 + (l & 15);
        const int cb = biasPerm ? ((col >> 4) + (col & 15) * 128) : col;
        const float bvv = bias[cb];
        #pragma unroll
        for (int mi = 0; mi < 4; ++mi) {
            #pragma unroll
            for (int r = 0; r < 4; ++r) {
                const int rowg = m0 + wr + mi*16 + (l >> 4) * 4 + r;
                float v = acc[mi][ni][r] + bvv;
                if (EPI == 1) v = fmaxf(v, 0.0f);
                const size_t idx = (size_t)rowg * N + col;
                if (EPI == 2) outF[idx] = v + resid[idx];
                else outB[idx] = f2bf(v);
            }
        }
    }
}

// ---------------- per-token attention: scores(K=16, 32x32x16), softmax, PV(16x16x32)
// Qt/Kt rows in [a*16+h] layout (from permuted weights); Vp rows in [h*128+b]; out Cc [h*128+a]
__global__ __launch_bounds__(256) void attn_tok(
        const unsigned short* __restrict__ Qt, const unsigned short* __restrict__ Kt,
        const unsigned short* __restrict__ Vp, unsigned short* __restrict__ Cc) {
    const int n = blockIdx.x;
    const int t = threadIdx.x, w = t >> 6, l = t & 63;
    __shared__ __align__(16) unsigned short q_s[128 * 24];
    __shared__ __align__(16) unsigned short k_s[128 * 24];
    __shared__ __align__(16) unsigned short v_s[16 * 136];
    __shared__ __align__(16) unsigned short p_s[128 * 136];
    __shared__ __align__(16) unsigned short c_s[2048];
    {
        const size_t base = (size_t)n * DM + t * 8;
        short8 qv = *(const short8*)(Qt + base);
        short8 kv = *(const short8*)(Kt + base);
        short8 vv = *(const short8*)(Vp + base);
        const int a = t >> 1, h0 = (t & 1) * 8;
        *(short8*)(q_s + a * 24 + h0) = qv;
        *(short8*)(k_s + a * 24 + h0) = kv;
        *(short8*)(v_s + (t >> 4) * 136 + (t & 15) * 8) = vv;
    }
    __syncthreads();
    // scores: wave w owns rows a in [w*32, w*32+32)
    f32x16 sc[4];
    {
        const short8 aq = *(const short8*)(q_s + (w*32 + (l & 31)) * 24 + (l >> 5) * 8);
        f32x16 z = {};
        #pragma unroll
        for (int bt = 0; bt < 4; ++bt) {
            const short8 bk2 = *(const short8*)(k_s + (bt*32 + (l & 31)) * 24 + (l >> 5) * 8);
            sc[bt] = __builtin_amdgcn_mfma_f32_32x32x16_bf16(aq, bk2, z, 0, 0, 0);
        }
    }
    const float isq = 0.088388347648318447f; // 1/sqrt(128)
    #pragma unroll
    for (int r = 0; r < 16; ++r) {
        float x0 = sc[0][r]*isq, x1 = sc[1][r]*isq, x2 = sc[2][r]*isq, x3 = sc[3][r]*isq;
        float mx = fmaxf(fmaxf(x0, x1), fmaxf(x2, x3));
        #pragma unroll
        for (int d = 1; d < 32; d <<= 1) mx = fmaxf(mx, __shfl_xor(mx, d));
        const float e0 = __expf(x0 - mx), e1 = __expf(x1 - mx),
                    e2 = __expf(x2 - mx), e3 = __expf(x3 - mx);
        float sm = (e0 + e1) + (e2 + e3);
        #pragma unroll
        for (int d = 1; d < 32; d <<= 1) sm += __shfl_xor(sm, d);
        const float inv = 1.0f / sm;
        const int arow = w*32 + (r & 3) + 8*(r >> 2) + 4*(l >> 5);
        unsigned short* pr = p_s + arow * 136 + (l & 31);
        pr[0]  = f2bf(e0 * inv);
        pr[32] = f2bf(e1 * inv);
        pr[64] = f2bf(e2 * inv);
        pr[96] = f2bf(e3 * inv);
    }
    __syncthreads();
    f32x4 pv[2] = {};
    #pragma unroll
    for (int ks = 0; ks < 4; ++ks) {
        const short8 bv = *(const short8*)(v_s + (l & 15) * 136 + ks*32 + (l >> 4) * 8);
        #pragma unroll
        for (int at = 0; at < 2; ++at) {
            const short8 ap = *(const short8*)(p_s + (w*32 + at*16 + (l & 15)) * 136 + ks*32 + (l >> 4) * 8);
            pv[at] = __builtin_amdgcn_mfma_f32_16x16x32_bf16(ap, bv, pv[at], 0, 0, 0);
        }
    }
    #pragma unroll
    for (int at = 0; at < 2; ++at) {
        const int a0 = w*32 + at*16 + ((l >> 4) << 2);
        short4v pk;
        #pragma unroll
        for (int r = 0; r < 4; ++r) pk[r] = (short)f2bf(pv[at][r]);
        *(short4v*)(c_s + (l & 15) * 128 + a0) = pk;
    }
    __syncthreads();
    *(short8*)(Cc + (size_t)n * DM + t * 8) = *(const short8*)(c_s + t * 8);
}

extern "C" void kernel_launch(void* const* d_in, const int* in_sizes, int n_in,
                              void* d_out, int out_size, void* d_ws, size_t ws_size,
                              hipStream_t stream) {
    (void)in_sizes; (void)n_in; (void)out_size; (void)ws_size;
    const float* q    = (const float*)d_in[0];
    const float* k    = (const float*)d_in[1];
    const float* v    = (const float*)d_in[2];
    const float* nq_a = (const float*)d_in[3];
    const float* nq_b = (const float*)d_in[4];
    const float* nk_a = (const float*)d_in[5];
    const float* nk_b = (const float*)d_in[6];
    const float* nv_a = (const float*)d_in[7];
    const float* nv_b = (const float*)d_in[8];
    const float* n2_a = (const float*)d_in[9];
    const float* n2_b = (const float*)d_in[10];
    const float* Wq   = (const float*)d_in[11];
    const float* bq   = (const float*)d_in[12];
    const float* Wk   = (const float*)d_in[13];
    const float* bk   = (const float*)d_in[14];
    const float* Wv   = (const float*)d_in[15];
    const float* bv   = (const float*)d_in[16];
    const float* Wo   = (const float*)d_in[17];
    const float* bo   = (const float*)d_in[18];
    const float* W1   = (const float*)d_in[19];
    const float* b1   = (const float*)d_in[20];
    const float* W2   = (const float*)d_in[21];
    const float* b2   = (const float*)d_in[22];

    char* ws = (char*)d_ws;
    const size_t MB = 1024 * 1024;
    unsigned short* buf0 = (unsigned short*)(ws);            // 32MB: qn/kn/vn then concat
    unsigned short* QtB  = (unsigned short*)(ws + 32*MB);    // 32MB: Qt, later x2
    unsigned short* KtB  = (unsigned short*)(ws + 64*MB);    // 32MB: Kt, later h1
    unsigned short* VpB  = (unsigned short*)(ws + 96*MB);    // 32MB: Vp
    unsigned short* Wqt  = (unsigned short*)(ws + 128*MB);   // 6 x 8MB weights
    unsigned short* Wkt  = (unsigned short*)(ws + 136*MB);
    unsigned short* Wvt  = (unsigned short*)(ws + 144*MB);
    unsigned short* Wot  = (unsigned short*)(ws + 152*MB);
    unsigned short* W1t  = (unsigned short*)(ws + 160*MB);
    unsigned short* W2t  = (unsigned short*)(ws + 168*MB);
    unsigned short* x2   = QtB;
    unsigned short* h1   = KtB;
    float* x = (float*)d_out;   // residual stream lives in d_out

    dim3 b256(256);
    dim3 gT(DM / 32, DM / 32);
    wtrans<<<gT, b256, 0, stream>>>(Wq, Wqt, 1);
    wtrans<<<gT, b256, 0, stream>>>(Wk, Wkt, 1);
    wtrans<<<gT, b256, 0, stream>>>(Wv, Wvt, 0);
    wtrans<<<gT, b256, 0, stream>>>(Wo, Wot, 0);
    wtrans<<<gT, b256, 0, stream>>>(W1, W1t, 0);
    wtrans<<<gT, b256, 0, stream>>>(W2, W2t, 0);

    dim3 gN(NTOK);
    dim3 gG(DM / 128, NTOK / 128);

    norm_rows<<<gN, b256, 0, stream>>>(q, nq_a, nq_b, buf0);
    gemm_bt<0><<<gG, b256, 0, stream>>>(buf0, Wqt, bq, nullptr, nullptr, QtB, NTOK, DM, DM, 1);
    norm_rows<<<gN, b256, 0, stream>>>(k, nk_a, nk_b, buf0);
    gemm_bt<0><<<gG, b256, 0, stream>>>(buf0, Wkt, bk, nullptr, nullptr, KtB, NTOK, DM, DM, 1);
    norm_rows<<<gN, b256, 0, stream>>>(v, nv_a, nv_b, buf0);
    gemm_bt<0><<<gG, b256, 0, stream>>>(buf0, Wvt, bv, nullptr, nullptr, VpB, NTOK, DM, DM, 0);
    attn_tok<<<gN, b256, 0, stream>>>(QtB, KtB, VpB, buf0);
    gemm_bt<2><<<gG, b256, 0, stream>>>(buf0, Wot, bo, v, x, nullptr, NTOK, DM, DM, 0);
    norm_rows<<<gN, b256, 0, stream>>>(x, n2_a, n2_b, x2);
    gemm_bt<1><<<gG, b256, 0, stream>>>(x2, W1t, b1, nullptr, nullptr, h1, NTOK, DM, DM, 0);
    gemm_bt<2><<<gG, b256, 0, stream>>>(h1, W2t, b2, x, x, nullptr, NTOK, DM, DM, 0);
}

// Round 2
// 700.987 us; speedup vs baseline: 1.3084x; 1.3084x over previous
//
#include <hip/hip_runtime.h>
#include <hip/hip_bf16.h>

#define DM 2048
#define NTOK 8192
#define EPS 1e-6f

typedef __attribute__((ext_vector_type(8))) short short8;
typedef __attribute__((ext_vector_type(4))) short short4v;
typedef __attribute__((ext_vector_type(4))) float f32x4;
typedef __attribute__((ext_vector_type(16))) float f32x16;

typedef const __attribute__((address_space(1))) void gvoid;
typedef __attribute__((address_space(3))) void lvoid;

static __device__ __forceinline__ unsigned short f2bf(float f) {
    unsigned u = __builtin_bit_cast(unsigned, f);
    unsigned r = u + 0x7FFFu + ((u >> 16) & 1u);
    return (unsigned short)(r >> 16);
}

// ---------------- row norm: alpha*(x-mu)/(std+eps)+beta, std ddof=1, f32 in -> bf16 out
__global__ __launch_bounds__(256) void norm_rows(
        const float* __restrict__ in, const float* __restrict__ alpha,
        const float* __restrict__ beta, unsigned short* __restrict__ out) {
    const int row = blockIdx.x;
    const int t = threadIdx.x;
    const float* x = in + (size_t)row * DM + t * 8;
    float4 v0 = *(const float4*)(x);
    float4 v1 = *(const float4*)(x + 4);
    float s = (v0.x + v0.y) + (v0.z + v0.w) + (v1.x + v1.y) + (v1.z + v1.w);
    float ss = v0.x*v0.x + v0.y*v0.y + v0.z*v0.z + v0.w*v0.w
             + v1.x*v1.x + v1.y*v1.y + v1.z*v1.z + v1.w*v1.w;
    #pragma unroll
    for (int m = 1; m < 64; m <<= 1) {
        s  += __shfl_xor(s, m);
        ss += __shfl_xor(ss, m);
    }
    __shared__ float red[8];
    const int wv = t >> 6, ln = t & 63;
    if (ln == 0) { red[wv] = s; red[4 + wv] = ss; }
    __syncthreads();
    s  = (red[0] + red[1]) + (red[2] + red[3]);
    ss = (red[4] + red[5]) + (red[6] + red[7]);
    const float mu = s * (1.0f / DM);
    float var = (ss - s * mu) * (1.0f / (DM - 1));
    var = fmaxf(var, 0.0f);
    const float scale = 1.0f / (sqrtf(var) + EPS);
    float4 a0 = *(const float4*)(alpha + t*8);
    float4 a1 = *(const float4*)(alpha + t*8 + 4);
    float4 b0 = *(const float4*)(beta + t*8);
    float4 b1 = *(const float4*)(beta + t*8 + 4);
    short8 o;
    o[0] = (short)f2bf(a0.x * (v0.x - mu) * scale + b0.x);
    o[1] = (short)f2bf(a0.y * (v0.y - mu) * scale + b0.y);
    o[2] = (short)f2bf(a0.z * (v0.z - mu) * scale + b0.z);
    o[3] = (short)f2bf(a0.w * (v0.w - mu) * scale + b0.w);
    o[4] = (short)f2bf(a1.x * (v1.x - mu) * scale + b1.x);
    o[5] = (short)f2bf(a1.y * (v1.y - mu) * scale + b1.y);
    o[6] = (short)f2bf(a1.z * (v1.z - mu) * scale + b1.z);
    o[7] = (short)f2bf(a1.w * (v1.w - mu) * scale + b1.w);
    *(short8*)(out + (size_t)row * DM + t * 8) = o;
}

// ---------------- weight transpose+cast: Wt[pc][k] = bf16(W[k][c]); perm: pc=(c&127)*16+(c>>7)
__global__ __launch_bounds__(256) void wtrans(
        const float* __restrict__ W, unsigned short* __restrict__ Wt, int perm) {
    __shared__ float tile[32][33];
    const int bc = blockIdx.x * 32, bk = blockIdx.y * 32;
    const int t = threadIdx.x;
    const int tc = t & 31, tr = t >> 5;
    #pragma unroll
    for (int i = 0; i < 4; ++i)
        tile[tr + i*8][tc] = W[(size_t)(bk + tr + i*8) * DM + bc + tc];
    __syncthreads();
    #pragma unroll
    for (int i = 0; i < 4; ++i) {
        const int c = bc + tr + i*8;
        const int pc = perm ? ((c & 127) * 16 + (c >> 7)) : c;
        Wt[(size_t)pc * DM + bk + tc] = f2bf(tile[tc][tr + i*8]);
    }
}

// ---------------- 256x256x64 8-phase GEMM: C[8192,2048] = A[8192,2048]bf16 @ Bt[2048,2048]bf16^T
// T1 XCD swizzle + T2 LDS XOR swizzle + T3/T4 8-phase counted vmcnt + T5 setprio.
// EPI 0: bf16 out w/ bias. EPI 1: bf16 out w/ bias+relu. EPI 2: f32 out w/ bias+resid.
#define BARRIER __builtin_amdgcn_s_barrier()
#define WAIT_LGKM0 asm volatile("s_waitcnt lgkmcnt(0)" ::: "memory")
#define VMCNT(n) asm volatile("s_waitcnt vmcnt(" #n ")" ::: "memory")

template<int EPI>
__global__ __launch_bounds__(512, 2) void gemm256(
        const unsigned short* __restrict__ A, const unsigned short* __restrict__ Bt,
        const float* __restrict__ bias, const float* __restrict__ resid,
        float* __restrict__ outF, unsigned short* __restrict__ outB, int biasPerm) {
    __shared__ __align__(16) char lds[131072];   // A: 2x32KB @0, B: 2x32KB @64KB
    char* ldsA = lds;
    char* ldsB = lds + 65536;

    const int t = threadIdx.x, l = t & 63, w = t >> 6;
    const int wm = w >> 2, wn = w & 3;

    // T1: bijective XCD swizzle; XCD x gets one N-panel (B L2-resident), all M-tiles
    const int b = blockIdx.x;
    const int wg = (b & 7) * 32 + (b >> 3);
    const int n0 = (wg >> 5) * 256;
    const int m0 = (wg & 31) * 256;

    // staging: lds chunk ci=(i*512+t): row=i*64+(t>>3), chunk=t&7; global src chunk ^= row&7
    const int rS = t >> 3;
    const int cS = ((t & 7) ^ (rS & 7)) * 8;
    const unsigned short* aSt = A  + (size_t)(m0 + rS) * 2048 + cS;
    const unsigned short* bSt = Bt + (size_t)(n0 + rS) * 2048 + cS;
    const int ldsStW = w * 1024;

    // LDS read bases (swizzled): byte = r*128 + ((ks*4+(l>>4))^(l&7))*16
    const int aRd = wm * 16384 + (l & 15) * 128;
    const int bRd = (wn >> 1) * 16384 + (wn & 1) * 8192 + (l & 15) * 128;
    const int ch0 = (((l >> 4) + 0) ^ (l & 7)) * 16;
    const int ch1 = (((l >> 4) + 4) ^ (l & 7)) * 16;

    short8 af[4][2], bf[4][2];
    f32x4 acc[8][4] = {};

#define STG_A(buf, h, kt) do { \
    __builtin_amdgcn_global_load_lds((gvoid*)(aSt + (size_t)((h)*128)*2048 + (kt)*64), \
        (lvoid*)(ldsA + (buf)*32768 + (h)*16384 + ldsStW), 16, 0, 0); \
    __builtin_amdgcn_global_load_lds((gvoid*)(aSt + (size_t)((h)*128+64)*2048 + (kt)*64), \
        (lvoid*)(ldsA + (buf)*32768 + (h)*16384 + 8192 + ldsStW), 16, 0, 0); \
} while(0)
#define STG_B(buf, h, kt) do { \
    __builtin_amdgcn_global_load_lds((gvoid*)(bSt + (size_t)((h)*128)*2048 + (kt)*64), \
        (lvoid*)(ldsB + (buf)*32768 + (h)*16384 + ldsStW), 16, 0, 0); \
    __builtin_amdgcn_global_load_lds((gvoid*)(bSt + (size_t)((h)*128+64)*2048 + (kt)*64), \
        (lvoid*)(ldsB + (buf)*32768 + (h)*16384 + 8192 + ldsStW), 16, 0, 0); \
} while(0)
#define RD_A(buf, mh) do { \
    _Pragma("unroll") for (int ml = 0; ml < 4; ++ml) { \
        af[ml][0] = *(const short8*)(ldsA + (buf)*32768 + aRd + ((mh)*4+ml)*2048 + ch0); \
        af[ml][1] = *(const short8*)(ldsA + (buf)*32768 + aRd + ((mh)*4+ml)*2048 + ch1); \
    } } while(0)
#define RD_B(buf, nh) do { \
    _Pragma("unroll") for (int nl = 0; nl < 2; ++nl) { \
        bf[(nh)*2+nl][0] = *(const short8*)(ldsB + (buf)*32768 + bRd + ((nh)*2+nl)*2048 + ch0); \
        bf[(nh)*2+nl][1] = *(const short8*)(ldsB + (buf)*32768 + bRd + ((nh)*2+nl)*2048 + ch1); \
    } } while(0)
#define MM_Q(mh, nh) do { \
    __builtin_amdgcn_s_setprio(1); \
    _Pragma("unroll") for (int ml = 0; ml < 4; ++ml) \
    _Pragma("unroll") for (int nl = 0; nl < 2; ++nl) { \
        acc[(mh)*4+ml][(nh)*2+nl] = __builtin_amdgcn_mfma_f32_16x16x32_bf16( \
            af[ml][0], bf[(nh)*2+nl][0], acc[(mh)*4+ml][(nh)*2+nl], 0, 0, 0); \
        acc[(mh)*4+ml][(nh)*2+nl] = __builtin_amdgcn_mfma_f32_16x16x32_bf16( \
            af[ml][1], bf[(nh)*2+nl][1], acc[(mh)*4+ml][(nh)*2+nl], 0, 0, 0); \
    } \
    __builtin_amdgcn_s_setprio(0); \
} while(0)

    // prologue: kt0 fully, kt1 B-halves; retire kt0
    STG_B(0, 0, 0); STG_B(0, 1, 0); STG_A(0, 0, 0); STG_A(0, 1, 0);
    STG_B(1, 0, 1); STG_B(1, 1, 1);
    VMCNT(4);
    BARRIER;

    #pragma unroll 1
    for (int i = 0; i < 16; ++i) {
        const int kt1 = 2*i + 1, k2 = 2*i + 2, k3 = 2*i + 3;
        const bool more = (i < 15);
        // P1: kt0 quadrant (m0,n0); stage A0 of kt1
        RD_A(0, 0); RD_B(0, 0);
        STG_A(1, 0, kt1);
        BARRIER; WAIT_LGKM0;
        MM_Q(0, 0);
        BARRIER;
        // P2: (m0,n1); stage A1 of kt1
        RD_B(0, 1);
        STG_A(1, 1, kt1);
        BARRIER; WAIT_LGKM0;
        MM_Q(0, 1);
        BARRIER;
        // P3: (m1,n1); stage B0 of kt+2 (kt0's B fully read by end P2)
        RD_A(0, 1);
        if (more) STG_B(0, 0, k2);
        BARRIER; WAIT_LGKM0;
        MM_Q(1, 1);
        BARRIER;
        // P4: (m1,n0); stage B1 of kt+2; counted vmcnt retires all of kt1
        if (more) { STG_B(0, 1, k2); VMCNT(4); } else { VMCNT(0); }
        BARRIER;
        MM_Q(1, 0);
        BARRIER;
        // P5: kt1 quadrant (m0,n0); stage A0 of kt+2 (kt0's A fully read by end P3)
        RD_A(1, 0); RD_B(1, 0);
        if (more) STG_A(0, 0, k2);
        BARRIER; WAIT_LGKM0;
        MM_Q(0, 0);
        BARRIER;
        // P6: (m0,n1); stage A1 of kt+2
        RD_B(1, 1);
        if (more) STG_A(0, 1, k2);
        BARRIER; WAIT_LGKM0;
        MM_Q(0, 1);
        BARRIER;
        // P7: (m1,n1); stage B0 of kt+3 (kt1's B fully read by end P6)
        RD_A(1, 1);
        if (more) STG_B(1, 0, k3);
        BARRIER; WAIT_LGKM0;
        MM_Q(1, 1);
        BARRIER;
        // P8: (m1,n0); stage B1 of kt+3; counted vmcnt retires all of kt+2
        if (more) { STG_B(1, 1, k3); VMCNT(4); }
        BARRIER;
        MM_Q(1, 0);
        BARRIER;
    }

    // epilogue
    #pragma unroll
    for (int ni = 0; ni < 4; ++ni) {
        const int col = n0 + wn*64 + ni*16 + (l & 15);
        const int cb = biasPerm ? ((col >> 4) + (col & 15) * 128) : col;
        const float bvv = bias[cb];
        #pragma unroll
        for (int mi = 0; mi < 8; ++mi) {
            #pragma unroll
            for (int r = 0; r < 4; ++r) {
                const int rowg = m0 + wm*128 + mi*16 + (l >> 4)*4 + r;
                float vv = acc[mi][ni][r] + bvv;
                if (EPI == 1) vv = fmaxf(vv, 0.0f);
                const size_t idx = (size_t)rowg * 2048 + col;
                if (EPI == 2) outF[idx] = vv + resid[idx];
                else outB[idx] = f2bf(vv);
            }
        }
    }
#undef STG_A
#undef STG_B
#undef RD_A
#undef RD_B
#undef MM_Q
}

// ---------------- per-token attention: scores(K=16, 32x32x16), softmax, PV(16x16x32)
__global__ __launch_bounds__(256) void attn_tok(
        const unsigned short* __restrict__ Qt, const unsigned short* __restrict__ Kt,
        const unsigned short* __restrict__ Vp, unsigned short* __restrict__ Cc) {
    const int n = blockIdx.x;
    const int t = threadIdx.x, w = t >> 6, l = t & 63;
    __shared__ __align__(16) unsigned short q_s[128 * 24];
    __shared__ __align__(16) unsigned short k_s[128 * 24];
    __shared__ __align__(16) unsigned short v_s[16 * 136];
    __shared__ __align__(16) unsigned short p_s[128 * 136];
    __shared__ __align__(16) unsigned short c_s[2048];
    {
        const size_t base = (size_t)n * DM + t * 8;
        short8 qv = *(const short8*)(Qt + base);
        short8 kv = *(const short8*)(Kt + base);
        short8 vv = *(const short8*)(Vp + base);
        const int a = t >> 1, h0 = (t & 1) * 8;
        *(short8*)(q_s + a * 24 + h0) = qv;
        *(short8*)(k_s + a * 24 + h0) = kv;
        *(short8*)(v_s + (t >> 4) * 136 + (t & 15) * 8) = vv;
    }
    __syncthreads();
    f32x16 sc[4];
    {
        const short8 aq = *(const short8*)(q_s + (w*32 + (l & 31)) * 24 + (l >> 5) * 8);
        f32x16 z = {};
        #pragma unroll
        for (int bt = 0; bt < 4; ++bt) {
            const short8 bk2 = *(const short8*)(k_s + (bt*32 + (l & 31)) * 24 + (l >> 5) * 8);
            sc[bt] = __builtin_amdgcn_mfma_f32_32x32x16_bf16(aq, bk2, z, 0, 0, 0);
        }
    }
    const float isq = 0.088388347648318447f;
    #pragma unroll
    for (int r = 0; r < 16; ++r) {
        float x0 = sc[0][r]*isq, x1 = sc[1][r]*isq, x2 = sc[2][r]*isq, x3 = sc[3][r]*isq;
        float mx = fmaxf(fmaxf(x0, x1), fmaxf(x2, x3));
        #pragma unroll
        for (int d = 1; d < 32; d <<= 1) mx = fmaxf(mx, __shfl_xor(mx, d));
        const float e0 = __expf(x0 - mx), e1 = __expf(x1 - mx),
                    e2 = __expf(x2 - mx), e3 = __expf(x3 - mx);
        float sm = (e0 + e1) + (e2 + e3);
        #pragma unroll
        for (int d = 1; d < 32; d <<= 1) sm += __shfl_xor(sm, d);
        const float inv = 1.0f / sm;
        const int arow = w*32 + (r & 3) + 8*(r >> 2) + 4*(l >> 5);
        unsigned short* pr = p_s + arow * 136 + (l & 31);
        pr[0]  = f2bf(e0 * inv);
        pr[32] = f2bf(e1 * inv);
        pr[64] = f2bf(e2 * inv);
        pr[96] = f2bf(e3 * inv);
    }
    __syncthreads();
    f32x4 pv[2] = {};
    #pragma unroll
    for (int ks = 0; ks < 4; ++ks) {
        const short8 bv = *(const short8*)(v_s + (l & 15) * 136 + ks*32 + (l >> 4) * 8);
        #pragma unroll
        for (int at = 0; at < 2; ++at) {
            const short8 ap = *(const short8*)(p_s + (w*32 + at*16 + (l & 15)) * 136 + ks*32 + (l >> 4) * 8);
            pv[at] = __builtin_amdgcn_mfma_f32_16x16x32_bf16(ap, bv, pv[at], 0, 0, 0);
        }
    }
    #pragma unroll
    for (int at = 0; at < 2; ++at) {
        const int a0 = w*32 + at*16 + ((l >> 4) << 2);
        short4v pk;
        #pragma unroll
        for (int r = 0; r < 4; ++r) pk[r] = (short)f2bf(pv[at][r]);
        *(short4v*)(c_s + (l & 15) * 128 + a0) = pk;
    }
    __syncthreads();
    *(short8*)(Cc + (size_t)n * DM + t * 8) = *(const short8*)(c_s + t * 8);
}

extern "C" void kernel_launch(void* const* d_in, const int* in_sizes, int n_in,
                              void* d_out, int out_size, void* d_ws, size_t ws_size,
                              hipStream_t stream) {
    (void)in_sizes; (void)n_in; (void)out_size; (void)ws_size;
    const float* q    = (const float*)d_in[0];
    const float* k    = (const float*)d_in[1];
    const float* v    = (const float*)d_in[2];
    const float* nq_a = (const float*)d_in[3];
    const float* nq_b = (const float*)d_in[4];
    const float* nk_a = (const float*)d_in[5];
    const float* nk_b = (const float*)d_in[6];
    const float* nv_a = (const float*)d_in[7];
    const float* nv_b = (const float*)d_in[8];
    const float* n2_a = (const float*)d_in[9];
    const float* n2_b = (const float*)d_in[10];
    const float* Wq   = (const float*)d_in[11];
    const float* bq   = (const float*)d_in[12];
    const float* Wk   = (const float*)d_in[13];
    const float* bk   = (const float*)d_in[14];
    const float* Wv   = (const float*)d_in[15];
    const float* bv   = (const float*)d_in[16];
    const float* Wo   = (const float*)d_in[17];
    const float* bo   = (const float*)d_in[18];
    const float* W1   = (const float*)d_in[19];
    const float* b1   = (const float*)d_in[20];
    const float* W2   = (const float*)d_in[21];
    const float* b2   = (const float*)d_in[22];

    char* ws = (char*)d_ws;
    const size_t MB = 1024 * 1024;
    unsigned short* buf0 = (unsigned short*)(ws);
    unsigned short* QtB  = (unsigned short*)(ws + 32*MB);
    unsigned short* KtB  = (unsigned short*)(ws + 64*MB);
    unsigned short* VpB  = (unsigned short*)(ws + 96*MB);
    unsigned short* Wqt  = (unsigned short*)(ws + 128*MB);
    unsigned short* Wkt  = (unsigned short*)(ws + 136*MB);
    unsigned short* Wvt  = (unsigned short*)(ws + 144*MB);
    unsigned short* Wot  = (unsigned short*)(ws + 152*MB);
    unsigned short* W1t  = (unsigned short*)(ws + 160*MB);
    unsigned short* W2t  = (unsigned short*)(ws + 168*MB);
    unsigned short* x2   = QtB;
    unsigned short* h1   = KtB;
    float* x = (float*)d_out;

    dim3 b256(256);
    dim3 gT(DM / 32, DM / 32);
    wtrans<<<gT, b256, 0, stream>>>(Wq, Wqt, 1);
    wtrans<<<gT, b256, 0, stream>>>(Wk, Wkt, 1);
    wtrans<<<gT, b256, 0, stream>>>(Wv, Wvt, 0);
    wtrans<<<gT, b256, 0, stream>>>(Wo, Wot, 0);
    wtrans<<<gT, b256, 0, stream>>>(W1, W1t, 0);
    wtrans<<<gT, b256, 0, stream>>>(W2, W2t, 0);

    dim3 gN(NTOK);
    dim3 gG(256);
    dim3 b512(512);

    norm_rows<<<gN, b256, 0, stream>>>(q, nq_a, nq_b, buf0);
    gemm256<0><<<gG, b512, 0, stream>>>(buf0, Wqt, bq, nullptr, nullptr, QtB, 1);
    norm_rows<<<gN, b256, 0, stream>>>(k, nk_a, nk_b, buf0);
    gemm256<0><<<gG, b512, 0, stream>>>(buf0, Wkt, bk, nullptr, nullptr, KtB, 1);
    norm_rows<<<gN, b256, 0, stream>>>(v, nv_a, nv_b, buf0);
    gemm256<0><<<gG, b512, 0, stream>>>(buf0, Wvt, bv, nullptr, nullptr, VpB, 0);
    attn_tok<<<gN, b256, 0, stream>>>(QtB, KtB, VpB, buf0);
    gemm256<2><<<gG, b512, 0, stream>>>(buf0, Wot, bo, v, x, nullptr, 0);
    norm_rows<<<gN, b256, 0, stream>>>(x, n2_a, n2_b, x2);
    gemm256<1><<<gG, b512, 0, stream>>>(x2, W1t, b1, nullptr, nullptr, h1, 0);
    gemm256<2><<<gG, b512, 0, stream>>>(h1, W2t, b2, x, x, nullptr, 0);
}

// Round 3
// 638.325 us; speedup vs baseline: 1.4369x; 1.0982x over previous
//
#include <hip/hip_runtime.h>
#include <hip/hip_bf16.h>

#define DM 2048
#define NTOK 8192
#define EPS 1e-6f

typedef __attribute__((ext_vector_type(8))) short short8;
typedef __attribute__((ext_vector_type(4))) short short4v;
typedef __attribute__((ext_vector_type(4))) float f32x4;
typedef __attribute__((ext_vector_type(16))) float f32x16;
typedef __attribute__((ext_vector_type(4))) unsigned int u32x4;

typedef const __attribute__((address_space(1))) void gvoid;
typedef __attribute__((address_space(3))) void lvoid;

static __device__ __forceinline__ unsigned short f2bf(float f) {
    unsigned u = __builtin_bit_cast(unsigned, f);
    unsigned r = u + 0x7FFFu + ((u >> 16) & 1u);
    return (unsigned short)(r >> 16);
}

// ---------------- row norm: alpha*(x-mu)/(std+eps)+beta, std ddof=1, f32 in -> bf16 out
__global__ __launch_bounds__(256) void norm_rows(
        const float* __restrict__ in, const float* __restrict__ alpha,
        const float* __restrict__ beta, unsigned short* __restrict__ out) {
    const int row = blockIdx.x;
    const int t = threadIdx.x;
    const float* x = in + (size_t)row * DM + t * 8;
    float4 v0 = *(const float4*)(x);
    float4 v1 = *(const float4*)(x + 4);
    float s = (v0.x + v0.y) + (v0.z + v0.w) + (v1.x + v1.y) + (v1.z + v1.w);
    float ss = v0.x*v0.x + v0.y*v0.y + v0.z*v0.z + v0.w*v0.w
             + v1.x*v1.x + v1.y*v1.y + v1.z*v1.z + v1.w*v1.w;
    #pragma unroll
    for (int m = 1; m < 64; m <<= 1) {
        s  += __shfl_xor(s, m);
        ss += __shfl_xor(ss, m);
    }
    __shared__ float red[8];
    const int wv = t >> 6, ln = t & 63;
    if (ln == 0) { red[wv] = s; red[4 + wv] = ss; }
    __syncthreads();
    s  = (red[0] + red[1]) + (red[2] + red[3]);
    ss = (red[4] + red[5]) + (red[6] + red[7]);
    const float mu = s * (1.0f / DM);
    float var = (ss - s * mu) * (1.0f / (DM - 1));
    var = fmaxf(var, 0.0f);
    const float scale = 1.0f / (sqrtf(var) + EPS);
    float4 a0 = *(const float4*)(alpha + t*8);
    float4 a1 = *(const float4*)(alpha + t*8 + 4);
    float4 b0 = *(const float4*)(beta + t*8);
    float4 b1 = *(const float4*)(beta + t*8 + 4);
    short8 o;
    o[0] = (short)f2bf(a0.x * (v0.x - mu) * scale + b0.x);
    o[1] = (short)f2bf(a0.y * (v0.y - mu) * scale + b0.y);
    o[2] = (short)f2bf(a0.z * (v0.z - mu) * scale + b0.z);
    o[3] = (short)f2bf(a0.w * (v0.w - mu) * scale + b0.w);
    o[4] = (short)f2bf(a1.x * (v1.x - mu) * scale + b1.x);
    o[5] = (short)f2bf(a1.y * (v1.y - mu) * scale + b1.y);
    o[6] = (short)f2bf(a1.z * (v1.z - mu) * scale + b1.z);
    o[7] = (short)f2bf(a1.w * (v1.w - mu) * scale + b1.w);
    *(short8*)(out + (size_t)row * DM + t * 8) = o;
}

// ---------------- weight transpose+cast+scale: Wt[pc][k] = bf16(W[k][c]*wscale)
__global__ __launch_bounds__(256) void wtrans(
        const float* __restrict__ W, unsigned short* __restrict__ Wt, int perm, float wscale) {
    __shared__ float tile[32][33];
    const int bc = blockIdx.x * 32, bk = blockIdx.y * 32;
    const int t = threadIdx.x;
    const int tc = t & 31, tr = t >> 5;
    #pragma unroll
    for (int i = 0; i < 4; ++i)
        tile[tr + i*8][tc] = W[(size_t)(bk + tr + i*8) * DM + bc + tc];
    __syncthreads();
    #pragma unroll
    for (int i = 0; i < 4; ++i) {
        const int c = bc + tr + i*8;
        const int pc = perm ? ((c & 127) * 16 + (c >> 7)) : c;
        Wt[(size_t)pc * DM + bk + tc] = f2bf(tile[tc][tr + i*8] * wscale);
    }
}

// ---------------- 256x256x64 8-phase GEMM (T1+T2+T3/T4+T5)
#define BARRIER __builtin_amdgcn_s_barrier()
#define WAIT_LGKM0 asm volatile("s_waitcnt lgkmcnt(0)" ::: "memory")
#define VMCNT(n) asm volatile("s_waitcnt vmcnt(" #n ")" ::: "memory")

template<int EPI>
__global__ __launch_bounds__(512, 2) void gemm256(
        const unsigned short* __restrict__ A, const unsigned short* __restrict__ Bt,
        const float* __restrict__ bias, const float* __restrict__ resid,
        float* __restrict__ outF, unsigned short* __restrict__ outB, int biasPerm,
        float bscale) {
    __shared__ __align__(16) char lds[131072];
    char* ldsA = lds;
    char* ldsB = lds + 65536;

    const int t = threadIdx.x, l = t & 63, w = t >> 6;
    const int wm = w >> 2, wn = w & 3;

    const int b = blockIdx.x;
    const int wg = (b & 7) * 32 + (b >> 3);
    const int n0 = (wg >> 5) * 256;
    const int m0 = (wg & 31) * 256;

    const int rS = t >> 3;
    const int cS = ((t & 7) ^ (rS & 7)) * 8;
    const unsigned short* aSt = A  + (size_t)(m0 + rS) * 2048 + cS;
    const unsigned short* bSt = Bt + (size_t)(n0 + rS) * 2048 + cS;
    const int ldsStW = w * 1024;

    const int aRd = wm * 16384 + (l & 15) * 128;
    const int bRd = (wn >> 1) * 16384 + (wn & 1) * 8192 + (l & 15) * 128;
    const int ch0 = (((l >> 4) + 0) ^ (l & 7)) * 16;
    const int ch1 = (((l >> 4) + 4) ^ (l & 7)) * 16;

    short8 af[4][2], bf[4][2];
    f32x4 acc[8][4] = {};

#define STG_A(buf, h, kt) do { \
    __builtin_amdgcn_global_load_lds((gvoid*)(aSt + (size_t)((h)*128)*2048 + (kt)*64), \
        (lvoid*)(ldsA + (buf)*32768 + (h)*16384 + ldsStW), 16, 0, 0); \
    __builtin_amdgcn_global_load_lds((gvoid*)(aSt + (size_t)((h)*128+64)*2048 + (kt)*64), \
        (lvoid*)(ldsA + (buf)*32768 + (h)*16384 + 8192 + ldsStW), 16, 0, 0); \
} while(0)
#define STG_B(buf, h, kt) do { \
    __builtin_amdgcn_global_load_lds((gvoid*)(bSt + (size_t)((h)*128)*2048 + (kt)*64), \
        (lvoid*)(ldsB + (buf)*32768 + (h)*16384 + ldsStW), 16, 0, 0); \
    __builtin_amdgcn_global_load_lds((gvoid*)(bSt + (size_t)((h)*128+64)*2048 + (kt)*64), \
        (lvoid*)(ldsB + (buf)*32768 + (h)*16384 + 8192 + ldsStW), 16, 0, 0); \
} while(0)
#define RD_A(buf, mh) do { \
    _Pragma("unroll") for (int ml = 0; ml < 4; ++ml) { \
        af[ml][0] = *(const short8*)(ldsA + (buf)*32768 + aRd + ((mh)*4+ml)*2048 + ch0); \
        af[ml][1] = *(const short8*)(ldsA + (buf)*32768 + aRd + ((mh)*4+ml)*2048 + ch1); \
    } } while(0)
#define RD_B(buf, nh) do { \
    _Pragma("unroll") for (int nl = 0; nl < 2; ++nl) { \
        bf[(nh)*2+nl][0] = *(const short8*)(ldsB + (buf)*32768 + bRd + ((nh)*2+nl)*2048 + ch0); \
        bf[(nh)*2+nl][1] = *(const short8*)(ldsB + (buf)*32768 + bRd + ((nh)*2+nl)*2048 + ch1); \
    } } while(0)
#define MM_Q(mh, nh) do { \
    __builtin_amdgcn_s_setprio(1); \
    _Pragma("unroll") for (int ml = 0; ml < 4; ++ml) \
    _Pragma("unroll") for (int nl = 0; nl < 2; ++nl) { \
        acc[(mh)*4+ml][(nh)*2+nl] = __builtin_amdgcn_mfma_f32_16x16x32_bf16( \
            af[ml][0], bf[(nh)*2+nl][0], acc[(mh)*4+ml][(nh)*2+nl], 0, 0, 0); \
        acc[(mh)*4+ml][(nh)*2+nl] = __builtin_amdgcn_mfma_f32_16x16x32_bf16( \
            af[ml][1], bf[(nh)*2+nl][1], acc[(mh)*4+ml][(nh)*2+nl], 0, 0, 0); \
    } \
    __builtin_amdgcn_s_setprio(0); \
} while(0)

    STG_B(0, 0, 0); STG_B(0, 1, 0); STG_A(0, 0, 0); STG_A(0, 1, 0);
    STG_B(1, 0, 1); STG_B(1, 1, 1);
    VMCNT(4);
    BARRIER;

    #pragma unroll 1
    for (int i = 0; i < 16; ++i) {
        const int kt1 = 2*i + 1, k2 = 2*i + 2, k3 = 2*i + 3;
        const bool more = (i < 15);
        RD_A(0, 0); RD_B(0, 0);
        STG_A(1, 0, kt1);
        BARRIER; WAIT_LGKM0;
        MM_Q(0, 0);
        BARRIER;
        RD_B(0, 1);
        STG_A(1, 1, kt1);
        BARRIER; WAIT_LGKM0;
        MM_Q(0, 1);
        BARRIER;
        RD_A(0, 1);
        if (more) STG_B(0, 0, k2);
        BARRIER; WAIT_LGKM0;
        MM_Q(1, 1);
        BARRIER;
        if (more) { STG_B(0, 1, k2); VMCNT(4); } else { VMCNT(0); }
        BARRIER;
        MM_Q(1, 0);
        BARRIER;
        RD_A(1, 0); RD_B(1, 0);
        if (more) STG_A(0, 0, k2);
        BARRIER; WAIT_LGKM0;
        MM_Q(0, 0);
        BARRIER;
        RD_B(1, 1);
        if (more) STG_A(0, 1, k2);
        BARRIER; WAIT_LGKM0;
        MM_Q(0, 1);
        BARRIER;
        RD_A(1, 1);
        if (more) STG_B(1, 0, k3);
        BARRIER; WAIT_LGKM0;
        MM_Q(1, 1);
        BARRIER;
        if (more) { STG_B(1, 1, k3); VMCNT(4); }
        BARRIER;
        MM_Q(1, 0);
        BARRIER;
    }

    #pragma unroll
    for (int ni = 0; ni < 4; ++ni) {
        const int col = n0 + wn*64 + ni*16 + (l & 15);
        const int cb = biasPerm ? ((col >> 4) + (col & 15) * 128) : col;
        const float bvv = bias[cb] * bscale;
        #pragma unroll
        for (int mi = 0; mi < 8; ++mi) {
            #pragma unroll
            for (int r = 0; r < 4; ++r) {
                const int rowg = m0 + wm*128 + mi*16 + (l >> 4)*4 + r;
                float vv = acc[mi][ni][r] + bvv;
                if (EPI == 1) vv = fmaxf(vv, 0.0f);
                const size_t idx = (size_t)rowg * 2048 + col;
                if (EPI == 2) outF[idx] = vv + resid[idx];
                else outB[idx] = f2bf(vv);
            }
        }
    }
#undef STG_A
#undef STG_B
#undef RD_A
#undef RD_B
#undef MM_Q
}

// ---------------- per-token attention, fully in-register (swapped QK^T + cvt_pk/permlane)
// Qt pre-scaled by 1/sqrt(128) via folded Wq. Lane (q=l&31, hi=l>>5) holds S[q][b] for
// b = bt*32 + (r&3)+8*(r>>2)+4*hi. Softmax lane-local + 1 permlane32_swap per reduce.
__global__ __launch_bounds__(256) void attn_tok(
        const unsigned short* __restrict__ Qt, const unsigned short* __restrict__ Kt,
        const unsigned short* __restrict__ Vp, unsigned short* __restrict__ Cc) {
    const int n = blockIdx.x;
    const int t = threadIdx.x, w = t >> 6, l = t & 63;
    const int q31 = l & 31, hi = l >> 5;
    __shared__ __align__(16) unsigned short c_s[16 * 132];

    const size_t tb = (size_t)n * DM;
    const short8 qf = *(const short8*)(Qt + tb + (w*32 + q31)*16 + hi*8);
    short8 kf[4];
    #pragma unroll
    for (int bt = 0; bt < 4; ++bt)
        kf[bt] = *(const short8*)(Kt + tb + (bt*32 + q31)*16 + hi*8);
    short8 vf[8];
    #pragma unroll
    for (int ks = 0; ks < 8; ++ks)
        vf[ks] = *(const short8*)(Vp + tb + (q31 & 15)*128 + ks*16 + hi*8);

    const f32x16 z = {};
    f32x16 sc[4];
    #pragma unroll
    for (int bt = 0; bt < 4; ++bt)
        sc[bt] = __builtin_amdgcn_mfma_f32_32x32x16_bf16(kf[bt], qf, z, 0, 0, 0);

    // softmax over b (64 local values + partner half)
    float m0 = sc[0][0], m1 = sc[1][0], m2 = sc[2][0], m3 = sc[3][0];
    #pragma unroll
    for (int r = 1; r < 16; ++r) {
        m0 = fmaxf(m0, sc[0][r]); m1 = fmaxf(m1, sc[1][r]);
        m2 = fmaxf(m2, sc[2][r]); m3 = fmaxf(m3, sc[3][r]);
    }
    float mx = fmaxf(fmaxf(m0, m1), fmaxf(m2, m3));
    { float a2 = mx, b2 = mx;
      asm volatile("v_permlane32_swap_b32 %0, %1" : "+v"(a2), "+v"(b2));
      mx = fmaxf(a2, b2); }

    float p[4][16];
    float s0 = 0.f, s1 = 0.f, s2 = 0.f, s3 = 0.f;
    #pragma unroll
    for (int r = 0; r < 16; ++r) {
        p[0][r] = __expf(sc[0][r] - mx); s0 += p[0][r];
        p[1][r] = __expf(sc[1][r] - mx); s1 += p[1][r];
        p[2][r] = __expf(sc[2][r] - mx); s2 += p[2][r];
        p[3][r] = __expf(sc[3][r] - mx); s3 += p[3][r];
    }
    float sm = (s0 + s1) + (s2 + s3);
    { float a2 = sm, b2 = sm;
      asm volatile("v_permlane32_swap_b32 %0, %1" : "+v"(a2), "+v"(b2));
      sm = a2 + b2; }
    const float inv = __builtin_amdgcn_rcpf(sm);
    #pragma unroll
    for (int bt = 0; bt < 4; ++bt)
        #pragma unroll
        for (int r = 0; r < 16; ++r)
            p[bt][r] *= inv;

    // rebuild PV A-fragments in-register: per ks, 4 cvt_pk + 2 permlane32_swap.
    // reg index r=(b&3)+4*((b>>3)&3) doesn't encode bit2 of b (the hi bit) -> lane-uniform.
    f32x16 acc = {};
    #pragma unroll
    for (int ks = 0; ks < 8; ++ks) {
        const int bt = ks >> 1, r0 = (ks & 1) * 8;
        unsigned X0, Y0, X1, Y1;
        asm("v_cvt_pk_bf16_f32 %0, %1, %2" : "=v"(X0) : "v"(p[bt][r0+0]), "v"(p[bt][r0+1]));
        asm("v_cvt_pk_bf16_f32 %0, %1, %2" : "=v"(Y0) : "v"(p[bt][r0+4]), "v"(p[bt][r0+5]));
        asm("v_cvt_pk_bf16_f32 %0, %1, %2" : "=v"(X1) : "v"(p[bt][r0+2]), "v"(p[bt][r0+3]));
        asm("v_cvt_pk_bf16_f32 %0, %1, %2" : "=v"(Y1) : "v"(p[bt][r0+6]), "v"(p[bt][r0+7]));
        asm volatile("v_permlane32_swap_b32 %0, %1" : "+v"(X0), "+v"(Y0));
        asm volatile("v_permlane32_swap_b32 %0, %1" : "+v"(X1), "+v"(Y1));
        u32x4 pw; pw[0] = X0; pw[1] = X1; pw[2] = Y0; pw[3] = Y1;
        const short8 paf = __builtin_bit_cast(short8, pw);
        acc = __builtin_amdgcn_mfma_f32_32x32x16_bf16(paf, vf[ks], acc, 0, 0, 0);
    }

    // epilogue: C[a][h] (col=h=l&31 valid <16, rows via regs) -> c_s[h][a] -> coalesced store
    if (q31 < 16) {
        #pragma unroll
        for (int rp = 0; rp < 8; ++rp) {
            const int r = rp * 2;
            const int a = (r & 3) + 8 * (r >> 2) + 4 * hi;
            unsigned pk;
            asm("v_cvt_pk_bf16_f32 %0, %1, %2" : "=v"(pk) : "v"(acc[r]), "v"(acc[r+1]));
            *(unsigned*)((char*)c_s + q31*264 + (w*32 + a)*2) = pk;
        }
    }
    __syncthreads();
    *(short8*)(Cc + tb + t*8) = *(const short8*)((char*)c_s + (t >> 4)*264 + (t & 15)*16);
}

extern "C" void kernel_launch(void* const* d_in, const int* in_sizes, int n_in,
                              void* d_out, int out_size, void* d_ws, size_t ws_size,
                              hipStream_t stream) {
    (void)in_sizes; (void)n_in; (void)out_size; (void)ws_size;
    const float* q    = (const float*)d_in[0];
    const float* k    = (const float*)d_in[1];
    const float* v    = (const float*)d_in[2];
    const float* nq_a = (const float*)d_in[3];
    const float* nq_b = (const float*)d_in[4];
    const float* nk_a = (const float*)d_in[5];
    const float* nk_b = (const float*)d_in[6];
    const float* nv_a = (const float*)d_in[7];
    const float* nv_b = (const float*)d_in[8];
    const float* n2_a = (const float*)d_in[9];
    const float* n2_b = (const float*)d_in[10];
    const float* Wq   = (const float*)d_in[11];
    const float* bq   = (const float*)d_in[12];
    const float* Wk   = (const float*)d_in[13];
    const float* bk   = (const float*)d_in[14];
    const float* Wv   = (const float*)d_in[15];
    const float* bv   = (const float*)d_in[16];
    const float* Wo   = (const float*)d_in[17];
    const float* bo   = (const float*)d_in[18];
    const float* W1   = (const float*)d_in[19];
    const float* b1   = (const float*)d_in[20];
    const float* W2   = (const float*)d_in[21];
    const float* b2   = (const float*)d_in[22];

    char* ws = (char*)d_ws;
    const size_t MB = 1024 * 1024;
    unsigned short* buf0 = (unsigned short*)(ws);
    unsigned short* QtB  = (unsigned short*)(ws + 32*MB);
    unsigned short* KtB  = (unsigned short*)(ws + 64*MB);
    unsigned short* VpB  = (unsigned short*)(ws + 96*MB);
    unsigned short* Wqt  = (unsigned short*)(ws + 128*MB);
    unsigned short* Wkt  = (unsigned short*)(ws + 136*MB);
    unsigned short* Wvt  = (unsigned short*)(ws + 144*MB);
    unsigned short* Wot  = (unsigned short*)(ws + 152*MB);
    unsigned short* W1t  = (unsigned short*)(ws + 160*MB);
    unsigned short* W2t  = (unsigned short*)(ws + 168*MB);
    unsigned short* x2   = QtB;
    unsigned short* h1   = KtB;
    float* x = (float*)d_out;

    const float isq = 0.088388347648318447f; // 1/sqrt(128), folded into Wq/bq

    dim3 b256(256);
    dim3 gT(DM / 32, DM / 32);
    wtrans<<<gT, b256, 0, stream>>>(Wq, Wqt, 1, isq);
    wtrans<<<gT, b256, 0, stream>>>(Wk, Wkt, 1, 1.0f);
    wtrans<<<gT, b256, 0, stream>>>(Wv, Wvt, 0, 1.0f);
    wtrans<<<gT, b256, 0, stream>>>(Wo, Wot, 0, 1.0f);
    wtrans<<<gT, b256, 0, stream>>>(W1, W1t, 0, 1.0f);
    wtrans<<<gT, b256, 0, stream>>>(W2, W2t, 0, 1.0f);

    dim3 gN(NTOK);
    dim3 gG(256);
    dim3 b512(512);

    norm_rows<<<gN, b256, 0, stream>>>(q, nq_a, nq_b, buf0);
    gemm256<0><<<gG, b512, 0, stream>>>(buf0, Wqt, bq, nullptr, nullptr, QtB, 1, isq);
    norm_rows<<<gN, b256, 0, stream>>>(k, nk_a, nk_b, buf0);
    gemm256<0><<<gG, b512, 0, stream>>>(buf0, Wkt, bk, nullptr, nullptr, KtB, 1, 1.0f);
    norm_rows<<<gN, b256, 0, stream>>>(v, nv_a, nv_b, buf0);
    gemm256<0><<<gG, b512, 0, stream>>>(buf0, Wvt, bv, nullptr, nullptr, VpB, 0, 1.0f);
    attn_tok<<<gN, b256, 0, stream>>>(QtB, KtB, VpB, buf0);
    gemm256<2><<<gG, b512, 0, stream>>>(buf0, Wot, bo, v, x, nullptr, 0, 1.0f);
    norm_rows<<<gN, b256, 0, stream>>>(x, n2_a, n2_b, x2);
    gemm256<1><<<gG, b512, 0, stream>>>(x2, W1t, b1, nullptr, nullptr, h1, 0, 1.0f);
    gemm256<2><<<gG, b512, 0, stream>>>(h1, W2t, b2, x, x, nullptr, 0, 1.0f);
}

// Round 4
// 598.787 us; speedup vs baseline: 1.5317x; 1.0660x over previous
//
#include <hip/hip_runtime.h>
#include <hip/hip_bf16.h>

#define DM 2048
#define NTOK 8192
#define EPS 1e-6f

typedef __attribute__((ext_vector_type(8))) short short8;
typedef __attribute__((ext_vector_type(4))) short short4v;
typedef __attribute__((ext_vector_type(4))) float f32x4;
typedef __attribute__((ext_vector_type(16))) float f32x16;
typedef __attribute__((ext_vector_type(4))) unsigned int u32x4;

typedef const __attribute__((address_space(1))) void gvoid;
typedef __attribute__((address_space(3))) void lvoid;

static __device__ __forceinline__ unsigned short f2bf(float f) {
    unsigned u = __builtin_bit_cast(unsigned, f);
    unsigned r = u + 0x7FFFu + ((u >> 16) & 1u);
    return (unsigned short)(r >> 16);
}
static __device__ __forceinline__ float bf2f(unsigned short h) {
    return __builtin_bit_cast(float, (unsigned)h << 16);
}

// ---------------- row norm (f32 in): alpha*(x-mu)/(std+eps)+beta, std ddof=1 -> bf16 out
__global__ __launch_bounds__(256) void norm_rows(
        const float* __restrict__ in, const float* __restrict__ alpha,
        const float* __restrict__ beta, unsigned short* __restrict__ out) {
    const int row = blockIdx.x;
    const int t = threadIdx.x;
    const float* x = in + (size_t)row * DM + t * 8;
    float4 v0 = *(const float4*)(x);
    float4 v1 = *(const float4*)(x + 4);
    float s = (v0.x + v0.y) + (v0.z + v0.w) + (v1.x + v1.y) + (v1.z + v1.w);
    float ss = v0.x*v0.x + v0.y*v0.y + v0.z*v0.z + v0.w*v0.w
             + v1.x*v1.x + v1.y*v1.y + v1.z*v1.z + v1.w*v1.w;
    #pragma unroll
    for (int m = 1; m < 64; m <<= 1) {
        s  += __shfl_xor(s, m);
        ss += __shfl_xor(ss, m);
    }
    __shared__ float red[8];
    const int wv = t >> 6, ln = t & 63;
    if (ln == 0) { red[wv] = s; red[4 + wv] = ss; }
    __syncthreads();
    s  = (red[0] + red[1]) + (red[2] + red[3]);
    ss = (red[4] + red[5]) + (red[6] + red[7]);
    const float mu = s * (1.0f / DM);
    float var = (ss - s * mu) * (1.0f / (DM - 1));
    var = fmaxf(var, 0.0f);
    const float scale = 1.0f / (sqrtf(var) + EPS);
    float4 a0 = *(const float4*)(alpha + t*8);
    float4 a1 = *(const float4*)(alpha + t*8 + 4);
    float4 b0 = *(const float4*)(beta + t*8);
    float4 b1 = *(const float4*)(beta + t*8 + 4);
    short8 o;
    o[0] = (short)f2bf(a0.x * (v0.x - mu) * scale + b0.x);
    o[1] = (short)f2bf(a0.y * (v0.y - mu) * scale + b0.y);
    o[2] = (short)f2bf(a0.z * (v0.z - mu) * scale + b0.z);
    o[3] = (short)f2bf(a0.w * (v0.w - mu) * scale + b0.w);
    o[4] = (short)f2bf(a1.x * (v1.x - mu) * scale + b1.x);
    o[5] = (short)f2bf(a1.y * (v1.y - mu) * scale + b1.y);
    o[6] = (short)f2bf(a1.z * (v1.z - mu) * scale + b1.z);
    o[7] = (short)f2bf(a1.w * (v1.w - mu) * scale + b1.w);
    *(short8*)(out + (size_t)row * DM + t * 8) = o;
}

// ---------------- row norm (bf16 in) -> bf16 out
__global__ __launch_bounds__(256) void norm_rows_bf16(
        const unsigned short* __restrict__ in, const float* __restrict__ alpha,
        const float* __restrict__ beta, unsigned short* __restrict__ out) {
    const int row = blockIdx.x;
    const int t = threadIdx.x;
    short8 rv = *(const short8*)(in + (size_t)row * DM + t * 8);
    float xv[8];
    #pragma unroll
    for (int j = 0; j < 8; ++j) xv[j] = bf2f((unsigned short)rv[j]);
    float s = 0.f, ss = 0.f;
    #pragma unroll
    for (int j = 0; j < 8; ++j) { s += xv[j]; ss += xv[j]*xv[j]; }
    #pragma unroll
    for (int m = 1; m < 64; m <<= 1) {
        s  += __shfl_xor(s, m);
        ss += __shfl_xor(ss, m);
    }
    __shared__ float red[8];
    const int wv = t >> 6, ln = t & 63;
    if (ln == 0) { red[wv] = s; red[4 + wv] = ss; }
    __syncthreads();
    s  = (red[0] + red[1]) + (red[2] + red[3]);
    ss = (red[4] + red[5]) + (red[6] + red[7]);
    const float mu = s * (1.0f / DM);
    float var = (ss - s * mu) * (1.0f / (DM - 1));
    var = fmaxf(var, 0.0f);
    const float scale = 1.0f / (sqrtf(var) + EPS);
    short8 o;
    #pragma unroll
    for (int j = 0; j < 8; ++j) {
        const float av = alpha[t*8 + j], bv = beta[t*8 + j];
        o[j] = (short)f2bf(av * (xv[j] - mu) * scale + bv);
    }
    *(short8*)(out + (size_t)row * DM + t * 8) = o;
}

// ---------------- weight transpose+cast+scale: Wt[pc][k] = bf16(W[k][c]*wscale)
__global__ __launch_bounds__(256) void wtrans(
        const float* __restrict__ W, unsigned short* __restrict__ Wt, int perm, float wscale) {
    __shared__ float tile[32][33];
    const int bc = blockIdx.x * 32, bk = blockIdx.y * 32;
    const int t = threadIdx.x;
    const int tc = t & 31, tr = t >> 5;
    #pragma unroll
    for (int i = 0; i < 4; ++i)
        tile[tr + i*8][tc] = W[(size_t)(bk + tr + i*8) * DM + bc + tc];
    __syncthreads();
    #pragma unroll
    for (int i = 0; i < 4; ++i) {
        const int c = bc + tr + i*8;
        const int pc = perm ? ((c & 127) * 16 + (c >> 7)) : c;
        Wt[(size_t)pc * DM + bk + tc] = f2bf(tile[tc][tr + i*8] * wscale);
    }
}

// ---------------- 256x256x64 8-phase GEMM (T1 4Mx8N regions + T2 + T3/T4 + T5)
// EPI 0: bf16 out, bias. 1: bf16, bias+relu. 3: bf16, bias + f32 resid. 4: f32 out, bias + bf16 resid.
#define BARRIER __builtin_amdgcn_s_barrier()
#define WAIT_LGKM0 asm volatile("s_waitcnt lgkmcnt(0)" ::: "memory")
#define VMCNT(n) asm volatile("s_waitcnt vmcnt(" #n ")" ::: "memory")

template<int EPI>
__global__ __launch_bounds__(512, 2) void gemm256(
        const unsigned short* __restrict__ A, const unsigned short* __restrict__ Bt,
        const float* __restrict__ bias, const float* __restrict__ residF,
        const unsigned short* __restrict__ residB,
        float* __restrict__ outF, unsigned short* __restrict__ outB, int biasPerm,
        float bscale) {
    __shared__ __align__(16) char lds[131072];
    char* ldsA = lds;
    char* ldsB = lds + 65536;

    const int t = threadIdx.x, l = t & 63, w = t >> 6;
    const int wm = w >> 2, wn = w & 3;

    // T1: each XCD owns a 4M x 8N tile region (A slices shared by 8 blocks, B by 4)
    const int b = blockIdx.x;
    const int xcd = b & 7;
    const int j = b >> 3;
    const int m0 = (xcd * 4 + (j & 3)) * 256;
    const int n0 = (j >> 2) * 256;

    const int rS = t >> 3;
    const int cS = ((t & 7) ^ (rS & 7)) * 8;
    const unsigned short* aSt = A  + (size_t)(m0 + rS) * 2048 + cS;
    const unsigned short* bSt = Bt + (size_t)(n0 + rS) * 2048 + cS;
    const int ldsStW = w * 1024;

    const int aRd = wm * 16384 + (l & 15) * 128;
    const int bRd = (wn >> 1) * 16384 + (wn & 1) * 8192 + (l & 15) * 128;
    const int ch0 = (((l >> 4) + 0) ^ (l & 7)) * 16;
    const int ch1 = (((l >> 4) + 4) ^ (l & 7)) * 16;

    short8 af[4][2], bf[4][2];
    f32x4 acc[8][4] = {};

#define STG_A(buf, h, kt) do { \
    __builtin_amdgcn_global_load_lds((gvoid*)(aSt + (size_t)((h)*128)*2048 + (kt)*64), \
        (lvoid*)(ldsA + (buf)*32768 + (h)*16384 + ldsStW), 16, 0, 0); \
    __builtin_amdgcn_global_load_lds((gvoid*)(aSt + (size_t)((h)*128+64)*2048 + (kt)*64), \
        (lvoid*)(ldsA + (buf)*32768 + (h)*16384 + 8192 + ldsStW), 16, 0, 0); \
} while(0)
#define STG_B(buf, h, kt) do { \
    __builtin_amdgcn_global_load_lds((gvoid*)(bSt + (size_t)((h)*128)*2048 + (kt)*64), \
        (lvoid*)(ldsB + (buf)*32768 + (h)*16384 + ldsStW), 16, 0, 0); \
    __builtin_amdgcn_global_load_lds((gvoid*)(bSt + (size_t)((h)*128+64)*2048 + (kt)*64), \
        (lvoid*)(ldsB + (buf)*32768 + (h)*16384 + 8192 + ldsStW), 16, 0, 0); \
} while(0)
#define RD_A(buf, mh) do { \
    _Pragma("unroll") for (int ml = 0; ml < 4; ++ml) { \
        af[ml][0] = *(const short8*)(ldsA + (buf)*32768 + aRd + ((mh)*4+ml)*2048 + ch0); \
        af[ml][1] = *(const short8*)(ldsA + (buf)*32768 + aRd + ((mh)*4+ml)*2048 + ch1); \
    } } while(0)
#define RD_B(buf, nh) do { \
    _Pragma("unroll") for (int nl = 0; nl < 2; ++nl) { \
        bf[(nh)*2+nl][0] = *(const short8*)(ldsB + (buf)*32768 + bRd + ((nh)*2+nl)*2048 + ch0); \
        bf[(nh)*2+nl][1] = *(const short8*)(ldsB + (buf)*32768 + bRd + ((nh)*2+nl)*2048 + ch1); \
    } } while(0)
#define MM_Q(mh, nh) do { \
    __builtin_amdgcn_s_setprio(1); \
    _Pragma("unroll") for (int ml = 0; ml < 4; ++ml) \
    _Pragma("unroll") for (int nl = 0; nl < 2; ++nl) { \
        acc[(mh)*4+ml][(nh)*2+nl] = __builtin_amdgcn_mfma_f32_16x16x32_bf16( \
            af[ml][0], bf[(nh)*2+nl][0], acc[(mh)*4+ml][(nh)*2+nl], 0, 0, 0); \
        acc[(mh)*4+ml][(nh)*2+nl] = __builtin_amdgcn_mfma_f32_16x16x32_bf16( \
            af[ml][1], bf[(nh)*2+nl][1], acc[(mh)*4+ml][(nh)*2+nl], 0, 0, 0); \
    } \
    __builtin_amdgcn_s_setprio(0); \
} while(0)

    STG_B(0, 0, 0); STG_B(0, 1, 0); STG_A(0, 0, 0); STG_A(0, 1, 0);
    STG_B(1, 0, 1); STG_B(1, 1, 1);
    VMCNT(4);
    BARRIER;

    #pragma unroll 1
    for (int i = 0; i < 16; ++i) {
        const int kt1 = 2*i + 1, k2 = 2*i + 2, k3 = 2*i + 3;
        const bool more = (i < 15);
        RD_A(0, 0); RD_B(0, 0);
        STG_A(1, 0, kt1);
        BARRIER; WAIT_LGKM0;
        MM_Q(0, 0);
        BARRIER;
        RD_B(0, 1);
        STG_A(1, 1, kt1);
        BARRIER; WAIT_LGKM0;
        MM_Q(0, 1);
        BARRIER;
        RD_A(0, 1);
        if (more) STG_B(0, 0, k2);
        BARRIER; WAIT_LGKM0;
        MM_Q(1, 1);
        BARRIER;
        if (more) { STG_B(0, 1, k2); VMCNT(4); } else { VMCNT(0); }
        BARRIER;
        MM_Q(1, 0);
        BARRIER;
        RD_A(1, 0); RD_B(1, 0);
        if (more) STG_A(0, 0, k2);
        BARRIER; WAIT_LGKM0;
        MM_Q(0, 0);
        BARRIER;
        RD_B(1, 1);
        if (more) STG_A(0, 1, k2);
        BARRIER; WAIT_LGKM0;
        MM_Q(0, 1);
        BARRIER;
        RD_A(1, 1);
        if (more) STG_B(1, 0, k3);
        BARRIER; WAIT_LGKM0;
        MM_Q(1, 1);
        BARRIER;
        if (more) { STG_B(1, 1, k3); VMCNT(4); }
        BARRIER;
        MM_Q(1, 0);
        BARRIER;
    }

    #pragma unroll
    for (int ni = 0; ni < 4; ++ni) {
        const int col = n0 + wn*64 + ni*16 + (l & 15);
        const int cb = biasPerm ? ((col >> 4) + (col & 15) * 128) : col;
        const float bvv = bias[cb] * bscale;
        #pragma unroll
        for (int mi = 0; mi < 8; ++mi) {
            #pragma unroll
            for (int r = 0; r < 4; ++r) {
                const int rowg = m0 + wm*128 + mi*16 + (l >> 4)*4 + r;
                float vv = acc[mi][ni][r] + bvv;
                if (EPI == 1) vv = fmaxf(vv, 0.0f);
                const size_t idx = (size_t)rowg * 2048 + col;
                if (EPI == 3)      outB[idx] = f2bf(vv + residF[idx]);
                else if (EPI == 4) outF[idx] = vv + bf2f(residB[idx]);
                else               outB[idx] = f2bf(vv);
            }
        }
    }
#undef STG_A
#undef STG_B
#undef RD_A
#undef RD_B
#undef MM_Q
}

// ---------------- per-token attention, fully in-register (swapped QK^T + cvt_pk/permlane)
__global__ __launch_bounds__(256) void attn_tok(
        const unsigned short* __restrict__ Qt, const unsigned short* __restrict__ Kt,
        const unsigned short* __restrict__ Vp, unsigned short* __restrict__ Cc) {
    const int n = blockIdx.x;
    const int t = threadIdx.x, w = t >> 6, l = t & 63;
    const int q31 = l & 31, hi = l >> 5;
    __shared__ __align__(16) unsigned short c_s[16 * 132];

    const size_t tb = (size_t)n * DM;
    const short8 qf = *(const short8*)(Qt + tb + (w*32 + q31)*16 + hi*8);
    short8 kf[4];
    #pragma unroll
    for (int bt = 0; bt < 4; ++bt)
        kf[bt] = *(const short8*)(Kt + tb + (bt*32 + q31)*16 + hi*8);
    short8 vf[8];
    #pragma unroll
    for (int ks = 0; ks < 8; ++ks)
        vf[ks] = *(const short8*)(Vp + tb + (q31 & 15)*128 + ks*16 + hi*8);

    const f32x16 z = {};
    f32x16 sc[4];
    #pragma unroll
    for (int bt = 0; bt < 4; ++bt)
        sc[bt] = __builtin_amdgcn_mfma_f32_32x32x16_bf16(kf[bt], qf, z, 0, 0, 0);

    float m0 = sc[0][0], m1 = sc[1][0], m2 = sc[2][0], m3 = sc[3][0];
    #pragma unroll
    for (int r = 1; r < 16; ++r) {
        m0 = fmaxf(m0, sc[0][r]); m1 = fmaxf(m1, sc[1][r]);
        m2 = fmaxf(m2, sc[2][r]); m3 = fmaxf(m3, sc[3][r]);
    }
    float mx = fmaxf(fmaxf(m0, m1), fmaxf(m2, m3));
    { float a2 = mx, b2 = mx;
      asm volatile("v_permlane32_swap_b32 %0, %1" : "+v"(a2), "+v"(b2));
      mx = fmaxf(a2, b2); }

    float p[4][16];
    float s0 = 0.f, s1 = 0.f, s2 = 0.f, s3 = 0.f;
    #pragma unroll
    for (int r = 0; r < 16; ++r) {
        p[0][r] = __expf(sc[0][r] - mx); s0 += p[0][r];
        p[1][r] = __expf(sc[1][r] - mx); s1 += p[1][r];
        p[2][r] = __expf(sc[2][r] - mx); s2 += p[2][r];
        p[3][r] = __expf(sc[3][r] - mx); s3 += p[3][r];
    }
    float sm = (s0 + s1) + (s2 + s3);
    { float a2 = sm, b2 = sm;
      asm volatile("v_permlane32_swap_b32 %0, %1" : "+v"(a2), "+v"(b2));
      sm = a2 + b2; }
    const float inv = __builtin_amdgcn_rcpf(sm);
    #pragma unroll
    for (int bt = 0; bt < 4; ++bt)
        #pragma unroll
        for (int r = 0; r < 16; ++r)
            p[bt][r] *= inv;

    f32x16 acc = {};
    #pragma unroll
    for (int ks = 0; ks < 8; ++ks) {
        const int bt = ks >> 1, r0 = (ks & 1) * 8;
        unsigned X0, Y0, X1, Y1;
        asm("v_cvt_pk_bf16_f32 %0, %1, %2" : "=v"(X0) : "v"(p[bt][r0+0]), "v"(p[bt][r0+1]));
        asm("v_cvt_pk_bf16_f32 %0, %1, %2" : "=v"(Y0) : "v"(p[bt][r0+4]), "v"(p[bt][r0+5]));
        asm("v_cvt_pk_bf16_f32 %0, %1, %2" : "=v"(X1) : "v"(p[bt][r0+2]), "v"(p[bt][r0+3]));
        asm("v_cvt_pk_bf16_f32 %0, %1, %2" : "=v"(Y1) : "v"(p[bt][r0+6]), "v"(p[bt][r0+7]));
        asm volatile("v_permlane32_swap_b32 %0, %1" : "+v"(X0), "+v"(Y0));
        asm volatile("v_permlane32_swap_b32 %0, %1" : "+v"(X1), "+v"(Y1));
        u32x4 pw; pw[0] = X0; pw[1] = X1; pw[2] = Y0; pw[3] = Y1;
        const short8 paf = __builtin_bit_cast(short8, pw);
        acc = __builtin_amdgcn_mfma_f32_32x32x16_bf16(paf, vf[ks], acc, 0, 0, 0);
    }

    if (q31 < 16) {
        #pragma unroll
        for (int rp = 0; rp < 8; ++rp) {
            const int r = rp * 2;
            const int a = (r & 3) + 8 * (r >> 2) + 4 * hi;
            unsigned pk;
            asm("v_cvt_pk_bf16_f32 %0, %1, %2" : "=v"(pk) : "v"(acc[r]), "v"(acc[r+1]));
            *(unsigned*)((char*)c_s + q31*264 + (w*32 + a)*2) = pk;
        }
    }
    __syncthreads();
    *(short8*)(Cc + tb + t*8) = *(const short8*)((char*)c_s + (t >> 4)*264 + (t & 15)*16);
}

extern "C" void kernel_launch(void* const* d_in, const int* in_sizes, int n_in,
                              void* d_out, int out_size, void* d_ws, size_t ws_size,
                              hipStream_t stream) {
    (void)in_sizes; (void)n_in; (void)out_size; (void)ws_size;
    const float* q    = (const float*)d_in[0];
    const float* k    = (const float*)d_in[1];
    const float* v    = (const float*)d_in[2];
    const float* nq_a = (const float*)d_in[3];
    const float* nq_b = (const float*)d_in[4];
    const float* nk_a = (const float*)d_in[5];
    const float* nk_b = (const float*)d_in[6];
    const float* nv_a = (const float*)d_in[7];
    const float* nv_b = (const float*)d_in[8];
    const float* n2_a = (const float*)d_in[9];
    const float* n2_b = (const float*)d_in[10];
    const float* Wq   = (const float*)d_in[11];
    const float* bq   = (const float*)d_in[12];
    const float* Wk   = (const float*)d_in[13];
    const float* bk   = (const float*)d_in[14];
    const float* Wv   = (const float*)d_in[15];
    const float* bv   = (const float*)d_in[16];
    const float* Wo   = (const float*)d_in[17];
    const float* bo   = (const float*)d_in[18];
    const float* W1   = (const float*)d_in[19];
    const float* b1   = (const float*)d_in[20];
    const float* W2   = (const float*)d_in[21];
    const float* b2   = (const float*)d_in[22];

    char* ws = (char*)d_ws;
    const size_t MB = 1024 * 1024;
    unsigned short* buf0 = (unsigned short*)(ws);
    unsigned short* QtB  = (unsigned short*)(ws + 32*MB);
    unsigned short* KtB  = (unsigned short*)(ws + 64*MB);
    unsigned short* VpB  = (unsigned short*)(ws + 96*MB);
    unsigned short* Wqt  = (unsigned short*)(ws + 128*MB);
    unsigned short* Wkt  = (unsigned short*)(ws + 136*MB);
    unsigned short* Wvt  = (unsigned short*)(ws + 144*MB);
    unsigned short* Wot  = (unsigned short*)(ws + 152*MB);
    unsigned short* W1t  = (unsigned short*)(ws + 160*MB);
    unsigned short* W2t  = (unsigned short*)(ws + 168*MB);
    unsigned short* x2   = QtB;   // after Q consumed
    unsigned short* h1   = KtB;   // after K consumed
    unsigned short* xb   = VpB;   // bf16 residual stream, after V consumed
    float* x = (float*)d_out;     // final f32 output

    const float isq = 0.088388347648318447f; // 1/sqrt(128), folded into Wq/bq

    dim3 b256(256);
    dim3 gT(DM / 32, DM / 32);
    wtrans<<<gT, b256, 0, stream>>>(Wq, Wqt, 1, isq);
    wtrans<<<gT, b256, 0, stream>>>(Wk, Wkt, 1, 1.0f);
    wtrans<<<gT, b256, 0, stream>>>(Wv, Wvt, 0, 1.0f);
    wtrans<<<gT, b256, 0, stream>>>(Wo, Wot, 0, 1.0f);
    wtrans<<<gT, b256, 0, stream>>>(W1, W1t, 0, 1.0f);
    wtrans<<<gT, b256, 0, stream>>>(W2, W2t, 0, 1.0f);

    dim3 gN(NTOK);
    dim3 gG(256);
    dim3 b512(512);

    norm_rows<<<gN, b256, 0, stream>>>(q, nq_a, nq_b, buf0);
    gemm256<0><<<gG, b512, 0, stream>>>(buf0, Wqt, bq, nullptr, nullptr, nullptr, QtB, 1, isq);
    norm_rows<<<gN, b256, 0, stream>>>(k, nk_a, nk_b, buf0);
    gemm256<0><<<gG, b512, 0, stream>>>(buf0, Wkt, bk, nullptr, nullptr, nullptr, KtB, 1, 1.0f);
    norm_rows<<<gN, b256, 0, stream>>>(v, nv_a, nv_b, buf0);
    gemm256<0><<<gG, b512, 0, stream>>>(buf0, Wvt, bv, nullptr, nullptr, nullptr, VpB, 0, 1.0f);
    attn_tok<<<gN, b256, 0, stream>>>(QtB, KtB, VpB, buf0);
    gemm256<3><<<gG, b512, 0, stream>>>(buf0, Wot, bo, v, nullptr, nullptr, xb, 0, 1.0f);
    norm_rows_bf16<<<gN, b256, 0, stream>>>(xb, n2_a, n2_b, x2);
    gemm256<1><<<gG, b512, 0, stream>>>(x2, W1t, b1, nullptr, nullptr, nullptr, h1, 0, 1.0f);
    gemm256<4><<<gG, b512, 0, stream>>>(h1, W2t, b2, nullptr, xb, x, nullptr, 0, 1.0f);
}

// Round 5
// 579.676 us; speedup vs baseline: 1.5822x; 1.0330x over previous
//
#include <hip/hip_runtime.h>
#include <hip/hip_bf16.h>

#define DM 2048
#define NTOK 8192
#define EPS 1e-6f

typedef __attribute__((ext_vector_type(8))) short short8;
typedef __attribute__((ext_vector_type(4))) short short4v;
typedef __attribute__((ext_vector_type(4))) float f32x4;
typedef __attribute__((ext_vector_type(16))) float f32x16;
typedef __attribute__((ext_vector_type(4))) unsigned int u32x4;

typedef const __attribute__((address_space(1))) void gvoid;
typedef __attribute__((address_space(3))) void lvoid;

static __device__ __forceinline__ unsigned short f2bf(float f) {
    unsigned u = __builtin_bit_cast(unsigned, f);
    unsigned r = u + 0x7FFFu + ((u >> 16) & 1u);
    return (unsigned short)(r >> 16);
}
static __device__ __forceinline__ float bf2f(unsigned short h) {
    return __builtin_bit_cast(float, (unsigned)h << 16);
}

// ---------------- row norm (f32 in): alpha*(x-mu)/(std+eps)+beta, std ddof=1 -> bf16 out
__global__ __launch_bounds__(256) void norm_rows(
        const float* __restrict__ in, const float* __restrict__ alpha,
        const float* __restrict__ beta, unsigned short* __restrict__ out) {
    const int row = blockIdx.x;
    const int t = threadIdx.x;
    const float* x = in + (size_t)row * DM + t * 8;
    float4 v0 = *(const float4*)(x);
    float4 v1 = *(const float4*)(x + 4);
    float s = (v0.x + v0.y) + (v0.z + v0.w) + (v1.x + v1.y) + (v1.z + v1.w);
    float ss = v0.x*v0.x + v0.y*v0.y + v0.z*v0.z + v0.w*v0.w
             + v1.x*v1.x + v1.y*v1.y + v1.z*v1.z + v1.w*v1.w;
    #pragma unroll
    for (int m = 1; m < 64; m <<= 1) {
        s  += __shfl_xor(s, m);
        ss += __shfl_xor(ss, m);
    }
    __shared__ float red[8];
    const int wv = t >> 6, ln = t & 63;
    if (ln == 0) { red[wv] = s; red[4 + wv] = ss; }
    __syncthreads();
    s  = (red[0] + red[1]) + (red[2] + red[3]);
    ss = (red[4] + red[5]) + (red[6] + red[7]);
    const float mu = s * (1.0f / DM);
    float var = (ss - s * mu) * (1.0f / (DM - 1));
    var = fmaxf(var, 0.0f);
    const float scale = 1.0f / (sqrtf(var) + EPS);
    float4 a0 = *(const float4*)(alpha + t*8);
    float4 a1 = *(const float4*)(alpha + t*8 + 4);
    float4 b0 = *(const float4*)(beta + t*8);
    float4 b1 = *(const float4*)(beta + t*8 + 4);
    short8 o;
    o[0] = (short)f2bf(a0.x * (v0.x - mu) * scale + b0.x);
    o[1] = (short)f2bf(a0.y * (v0.y - mu) * scale + b0.y);
    o[2] = (short)f2bf(a0.z * (v0.z - mu) * scale + b0.z);
    o[3] = (short)f2bf(a0.w * (v0.w - mu) * scale + b0.w);
    o[4] = (short)f2bf(a1.x * (v1.x - mu) * scale + b1.x);
    o[5] = (short)f2bf(a1.y * (v1.y - mu) * scale + b1.y);
    o[6] = (short)f2bf(a1.z * (v1.z - mu) * scale + b1.z);
    o[7] = (short)f2bf(a1.w * (v1.w - mu) * scale + b1.w);
    *(short8*)(out + (size_t)row * DM + t * 8) = o;
}

// ---------------- row norm (bf16 in) -> bf16 out
__global__ __launch_bounds__(256) void norm_rows_bf16(
        const unsigned short* __restrict__ in, const float* __restrict__ alpha,
        const float* __restrict__ beta, unsigned short* __restrict__ out) {
    const int row = blockIdx.x;
    const int t = threadIdx.x;
    short8 rv = *(const short8*)(in + (size_t)row * DM + t * 8);
    float xv[8];
    #pragma unroll
    for (int j = 0; j < 8; ++j) xv[j] = bf2f((unsigned short)rv[j]);
    float s = 0.f, ss = 0.f;
    #pragma unroll
    for (int j = 0; j < 8; ++j) { s += xv[j]; ss += xv[j]*xv[j]; }
    #pragma unroll
    for (int m = 1; m < 64; m <<= 1) {
        s  += __shfl_xor(s, m);
        ss += __shfl_xor(ss, m);
    }
    __shared__ float red[8];
    const int wv = t >> 6, ln = t & 63;
    if (ln == 0) { red[wv] = s; red[4 + wv] = ss; }
    __syncthreads();
    s  = (red[0] + red[1]) + (red[2] + red[3]);
    ss = (red[4] + red[5]) + (red[6] + red[7]);
    const float mu = s * (1.0f / DM);
    float var = (ss - s * mu) * (1.0f / (DM - 1));
    var = fmaxf(var, 0.0f);
    const float scale = 1.0f / (sqrtf(var) + EPS);
    short8 o;
    #pragma unroll
    for (int j = 0; j < 8; ++j) {
        const float av = alpha[t*8 + j], bv = beta[t*8 + j];
        o[j] = (short)f2bf(av * (xv[j] - mu) * scale + bv);
    }
    *(short8*)(out + (size_t)row * DM + t * 8) = o;
}

// ---------------- fused weight transpose+cast+scale for all 6 weights (z picks matrix)
__global__ __launch_bounds__(256) void wtrans6(
        const float* __restrict__ Wq, const float* __restrict__ Wk,
        const float* __restrict__ Wv, const float* __restrict__ Wo,
        const float* __restrict__ W1, const float* __restrict__ W2,
        unsigned short* __restrict__ Tq, unsigned short* __restrict__ Tk,
        unsigned short* __restrict__ Tv, unsigned short* __restrict__ To,
        unsigned short* __restrict__ T1, unsigned short* __restrict__ T2,
        float isq) {
    __shared__ float tile[32][33];
    const int z = blockIdx.z;
    const float* W = z==0?Wq: z==1?Wk: z==2?Wv: z==3?Wo: z==4?W1: W2;
    unsigned short* Wt = z==0?Tq: z==1?Tk: z==2?Tv: z==3?To: z==4?T1: T2;
    const int perm = (z < 2) ? 1 : 0;
    const float ws = (z == 0) ? isq : 1.0f;
    const int bc = blockIdx.x * 32, bk = blockIdx.y * 32;
    const int t = threadIdx.x;
    const int tc = t & 31, tr = t >> 5;
    #pragma unroll
    for (int i = 0; i < 4; ++i)
        tile[tr + i*8][tc] = W[(size_t)(bk + tr + i*8) * DM + bc + tc];
    __syncthreads();
    #pragma unroll
    for (int i = 0; i < 4; ++i) {
        const int c = bc + tr + i*8;
        const int pc = perm ? ((c & 127) * 16 + (c >> 7)) : c;
        Wt[(size_t)pc * DM + bk + tc] = f2bf(tile[tc][tr + i*8] * ws);
    }
}

// ---------------- 256x256x64 8-phase GEMM, deep-prefetch slots + coalesced C via LDS
// EPI 0: bf16+bias. 1: bf16+bias+relu. 3: bf16+bias+f32 resid. 4: f32+bias+bf16 resid.
#define BARRIER __builtin_amdgcn_s_barrier()
#define WAIT_LGKM0 asm volatile("s_waitcnt lgkmcnt(0)" ::: "memory")
#define VMCNT(n) asm volatile("s_waitcnt vmcnt(" #n ")" ::: "memory")

template<int EPI>
__global__ __launch_bounds__(512, 2) void gemm256(
        const unsigned short* __restrict__ A, const unsigned short* __restrict__ Bt,
        const float* __restrict__ bias, const float* __restrict__ residF,
        const unsigned short* __restrict__ residB,
        float* __restrict__ outF, unsigned short* __restrict__ outB, int biasPerm,
        float bscale) {
    __shared__ __align__(16) char lds[131072];
    char* ldsA = lds;
    char* ldsB = lds + 65536;

    const int t = threadIdx.x, l = t & 63, w = t >> 6;
    const int wm = w >> 2, wn = w & 3;

    // T1: each XCD owns a 4M x 8N tile region
    const int b = blockIdx.x;
    const int xcd = b & 7;
    const int j = b >> 3;
    const int m0 = (xcd * 4 + (j & 3)) * 256;
    const int n0 = (j >> 2) * 256;

    const int rS = t >> 3;
    const int cS = ((t & 7) ^ (rS & 7)) * 8;
    const unsigned short* aSt = A  + (size_t)(m0 + rS) * 2048 + cS;
    const unsigned short* bSt = Bt + (size_t)(n0 + rS) * 2048 + cS;
    const int ldsStW = w * 1024;

    const int aRd = wm * 16384 + (l & 15) * 128;
    const int bRd = (wn >> 1) * 16384 + (wn & 1) * 8192 + (l & 15) * 128;
    const int ch0 = (((l >> 4) + 0) ^ (l & 7)) * 16;
    const int ch1 = (((l >> 4) + 4) ^ (l & 7)) * 16;

    short8 af[4][2], bf[4][2];
    f32x4 acc[8][4] = {};

#define STG_A(buf, h, kt) do { \
    __builtin_amdgcn_global_load_lds((gvoid*)(aSt + (size_t)((h)*128)*2048 + (kt)*64), \
        (lvoid*)(ldsA + (buf)*32768 + (h)*16384 + ldsStW), 16, 0, 0); \
    __builtin_amdgcn_global_load_lds((gvoid*)(aSt + (size_t)((h)*128+64)*2048 + (kt)*64), \
        (lvoid*)(ldsA + (buf)*32768 + (h)*16384 + 8192 + ldsStW), 16, 0, 0); \
} while(0)
#define STG_B(buf, h, kt) do { \
    __builtin_amdgcn_global_load_lds((gvoid*)(bSt + (size_t)((h)*128)*2048 + (kt)*64), \
        (lvoid*)(ldsB + (buf)*32768 + (h)*16384 + ldsStW), 16, 0, 0); \
    __builtin_amdgcn_global_load_lds((gvoid*)(bSt + (size_t)((h)*128+64)*2048 + (kt)*64), \
        (lvoid*)(ldsB + (buf)*32768 + (h)*16384 + 8192 + ldsStW), 16, 0, 0); \
} while(0)
#define RD_A(buf, mh) do { \
    _Pragma("unroll") for (int ml = 0; ml < 4; ++ml) { \
        af[ml][0] = *(const short8*)(ldsA + (buf)*32768 + aRd + ((mh)*4+ml)*2048 + ch0); \
        af[ml][1] = *(const short8*)(ldsA + (buf)*32768 + aRd + ((mh)*4+ml)*2048 + ch1); \
    } } while(0)
#define RD_B(buf, nh) do { \
    _Pragma("unroll") for (int nl = 0; nl < 2; ++nl) { \
        bf[(nh)*2+nl][0] = *(const short8*)(ldsB + (buf)*32768 + bRd + ((nh)*2+nl)*2048 + ch0); \
        bf[(nh)*2+nl][1] = *(const short8*)(ldsB + (buf)*32768 + bRd + ((nh)*2+nl)*2048 + ch1); \
    } } while(0)
#define MM_Q(mh, nh) do { \
    __builtin_amdgcn_s_setprio(1); \
    _Pragma("unroll") for (int ml = 0; ml < 4; ++ml) \
    _Pragma("unroll") for (int nl = 0; nl < 2; ++nl) { \
        acc[(mh)*4+ml][(nh)*2+nl] = __builtin_amdgcn_mfma_f32_16x16x32_bf16( \
            af[ml][0], bf[(nh)*2+nl][0], acc[(mh)*4+ml][(nh)*2+nl], 0, 0, 0); \
        acc[(mh)*4+ml][(nh)*2+nl] = __builtin_amdgcn_mfma_f32_16x16x32_bf16( \
            af[ml][1], bf[(nh)*2+nl][1], acc[(mh)*4+ml][(nh)*2+nl], 0, 0, 0); \
    } \
    __builtin_amdgcn_s_setprio(0); \
} while(0)

    // prologue: stage kt0 and kt1 fully; wait kt0
    STG_B(0, 0, 0); STG_B(0, 1, 0); STG_A(0, 0, 0); STG_A(0, 1, 0);
    STG_B(1, 0, 1); STG_B(1, 1, 1); STG_A(1, 0, 1); STG_A(1, 1, 1);
    VMCNT(8);
    BARRIER;

    #pragma unroll 1
    for (int i = 0; i < 16; ++i) {
        const int k2 = 2*i + 2, k3 = 2*i + 3;
        const bool more = (i < 15);
        // P1
        RD_A(0, 0); RD_B(0, 0);
        BARRIER; WAIT_LGKM0;
        MM_Q(0, 0);
        BARRIER;
        // P2
        RD_B(0, 1);
        BARRIER; WAIT_LGKM0;
        MM_Q(0, 1);
        BARRIER;
        // P3: buf0-B free -> stage B(k2) both halves
        RD_A(0, 1);
        if (more) { STG_B(0, 0, k2); STG_B(0, 1, k2); }
        BARRIER; WAIT_LGKM0;
        MM_Q(1, 1);
        BARRIER;
        // P4: buf0-A free -> stage A(k2); wait retires kt1's stages (4+ phases old)
        if (more) { STG_A(0, 0, k2); STG_A(0, 1, k2); VMCNT(8); } else { VMCNT(0); }
        BARRIER;
        MM_Q(1, 0);
        BARRIER;
        // P5
        RD_A(1, 0); RD_B(1, 0);
        BARRIER; WAIT_LGKM0;
        MM_Q(0, 0);
        BARRIER;
        // P6
        RD_B(1, 1);
        BARRIER; WAIT_LGKM0;
        MM_Q(0, 1);
        BARRIER;
        // P7: buf1-B free -> stage B(k3)
        RD_A(1, 1);
        if (more) { STG_B(1, 0, k3); STG_B(1, 1, k3); }
        BARRIER; WAIT_LGKM0;
        MM_Q(1, 1);
        BARRIER;
        // P8: buf1-A free -> stage A(k3); wait retires k2's stages (4+ phases old)
        if (more) { STG_A(1, 0, k3); STG_A(1, 1, k3); VMCNT(8); } else { VMCNT(0); }
        BARRIER;
        MM_Q(1, 0);
        BARRIER;
    }

    // ---- epilogue: stage bf16(acc+bias[+relu]) in LDS, coalesced full-row stores ----
    unsigned short* cs = (unsigned short*)lds;   // [128][260] padded (520B rows)
    #pragma unroll 1
    for (int pass = 0; pass < 2; ++pass) {
        BARRIER;
        if (wm == pass) {
            #pragma unroll
            for (int ni = 0; ni < 4; ++ni) {
                const int col = wn*64 + ni*16 + (l & 15);
                const int gcol = n0 + col;
                const int cb = biasPerm ? ((gcol >> 4) + (gcol & 15) * 128) : gcol;
                const float bvv = bias[cb] * bscale;
                #pragma unroll
                for (int mi = 0; mi < 8; ++mi) {
                    #pragma unroll
                    for (int r = 0; r < 4; ++r) {
                        const int row = mi*16 + (l >> 4)*4 + r;
                        float vv = acc[mi][ni][r] + bvv;
                        if (EPI == 1) vv = fmaxf(vv, 0.0f);
                        cs[row*260 + col] = f2bf(vv);
                    }
                }
            }
        }
        BARRIER;
        #pragma unroll
        for (int s = 0; s < 8; ++s) {
            const int row = (t >> 5) + s*16;
            const int seg = t & 31;
            short8 pk = *(const short8*)(cs + row*260 + seg*8);
            const int grow = m0 + pass*128 + row;
            const size_t gb = (size_t)grow * 2048 + n0 + seg*8;
            if (EPI == 3) {
                float4 r0 = *(const float4*)(residF + gb);
                float4 r1 = *(const float4*)(residF + gb + 4);
                short8 o;
                o[0] = (short)f2bf(bf2f((unsigned short)pk[0]) + r0.x);
                o[1] = (short)f2bf(bf2f((unsigned short)pk[1]) + r0.y);
                o[2] = (short)f2bf(bf2f((unsigned short)pk[2]) + r0.z);
                o[3] = (short)f2bf(bf2f((unsigned short)pk[3]) + r0.w);
                o[4] = (short)f2bf(bf2f((unsigned short)pk[4]) + r1.x);
                o[5] = (short)f2bf(bf2f((unsigned short)pk[5]) + r1.y);
                o[6] = (short)f2bf(bf2f((unsigned short)pk[6]) + r1.z);
                o[7] = (short)f2bf(bf2f((unsigned short)pk[7]) + r1.w);
                *(short8*)(outB + gb) = o;
            } else if (EPI == 4) {
                short8 rb = *(const short8*)(residB + gb);
                float4 o0, o1;
                o0.x = bf2f((unsigned short)pk[0]) + bf2f((unsigned short)rb[0]);
                o0.y = bf2f((unsigned short)pk[1]) + bf2f((unsigned short)rb[1]);
                o0.z = bf2f((unsigned short)pk[2]) + bf2f((unsigned short)rb[2]);
                o0.w = bf2f((unsigned short)pk[3]) + bf2f((unsigned short)rb[3]);
                o1.x = bf2f((unsigned short)pk[4]) + bf2f((unsigned short)rb[4]);
                o1.y = bf2f((unsigned short)pk[5]) + bf2f((unsigned short)rb[5]);
                o1.z = bf2f((unsigned short)pk[6]) + bf2f((unsigned short)rb[6]);
                o1.w = bf2f((unsigned short)pk[7]) + bf2f((unsigned short)rb[7]);
                *(float4*)(outF + gb) = o0;
                *(float4*)(outF + gb + 4) = o1;
            } else {
                *(short8*)(outB + gb) = pk;
            }
        }
    }
#undef STG_A
#undef STG_B
#undef RD_A
#undef RD_B
#undef MM_Q
}

// ---------------- per-token attention, fully in-register (swapped QK^T + cvt_pk/permlane)
__global__ __launch_bounds__(256) void attn_tok(
        const unsigned short* __restrict__ Qt, const unsigned short* __restrict__ Kt,
        const unsigned short* __restrict__ Vp, unsigned short* __restrict__ Cc) {
    const int n = blockIdx.x;
    const int t = threadIdx.x, w = t >> 6, l = t & 63;
    const int q31 = l & 31, hi = l >> 5;
    __shared__ __align__(16) unsigned short c_s[16 * 132];

    const size_t tb = (size_t)n * DM;
    const short8 qf = *(const short8*)(Qt + tb + (w*32 + q31)*16 + hi*8);
    short8 kf[4];
    #pragma unroll
    for (int bt = 0; bt < 4; ++bt)
        kf[bt] = *(const short8*)(Kt + tb + (bt*32 + q31)*16 + hi*8);
    short8 vf[8];
    #pragma unroll
    for (int ks = 0; ks < 8; ++ks)
        vf[ks] = *(const short8*)(Vp + tb + (q31 & 15)*128 + ks*16 + hi*8);

    const f32x16 z = {};
    f32x16 sc[4];
    #pragma unroll
    for (int bt = 0; bt < 4; ++bt)
        sc[bt] = __builtin_amdgcn_mfma_f32_32x32x16_bf16(kf[bt], qf, z, 0, 0, 0);

    float m0 = sc[0][0], m1 = sc[1][0], m2 = sc[2][0], m3 = sc[3][0];
    #pragma unroll
    for (int r = 1; r < 16; ++r) {
        m0 = fmaxf(m0, sc[0][r]); m1 = fmaxf(m1, sc[1][r]);
        m2 = fmaxf(m2, sc[2][r]); m3 = fmaxf(m3, sc[3][r]);
    }
    float mx = fmaxf(fmaxf(m0, m1), fmaxf(m2, m3));
    { float a2 = mx, b2 = mx;
      asm volatile("v_permlane32_swap_b32 %0, %1" : "+v"(a2), "+v"(b2));
      mx = fmaxf(a2, b2); }

    float p[4][16];
    float s0 = 0.f, s1 = 0.f, s2 = 0.f, s3 = 0.f;
    #pragma unroll
    for (int r = 0; r < 16; ++r) {
        p[0][r] = __expf(sc[0][r] - mx); s0 += p[0][r];
        p[1][r] = __expf(sc[1][r] - mx); s1 += p[1][r];
        p[2][r] = __expf(sc[2][r] - mx); s2 += p[2][r];
        p[3][r] = __expf(sc[3][r] - mx); s3 += p[3][r];
    }
    float sm = (s0 + s1) + (s2 + s3);
    { float a2 = sm, b2 = sm;
      asm volatile("v_permlane32_swap_b32 %0, %1" : "+v"(a2), "+v"(b2));
      sm = a2 + b2; }
    const float inv = __builtin_amdgcn_rcpf(sm);
    #pragma unroll
    for (int bt = 0; bt < 4; ++bt)
        #pragma unroll
        for (int r = 0; r < 16; ++r)
            p[bt][r] *= inv;

    f32x16 acc = {};
    #pragma unroll
    for (int ks = 0; ks < 8; ++ks) {
        const int bt = ks >> 1, r0 = (ks & 1) * 8;
        unsigned X0, Y0, X1, Y1;
        asm("v_cvt_pk_bf16_f32 %0, %1, %2" : "=v"(X0) : "v"(p[bt][r0+0]), "v"(p[bt][r0+1]));
        asm("v_cvt_pk_bf16_f32 %0, %1, %2" : "=v"(Y0) : "v"(p[bt][r0+4]), "v"(p[bt][r0+5]));
        asm("v_cvt_pk_bf16_f32 %0, %1, %2" : "=v"(X1) : "v"(p[bt][r0+2]), "v"(p[bt][r0+3]));
        asm("v_cvt_pk_bf16_f32 %0, %1, %2" : "=v"(Y1) : "v"(p[bt][r0+6]), "v"(p[bt][r0+7]));
        asm volatile("v_permlane32_swap_b32 %0, %1" : "+v"(X0), "+v"(Y0));
        asm volatile("v_permlane32_swap_b32 %0, %1" : "+v"(X1), "+v"(Y1));
        u32x4 pw; pw[0] = X0; pw[1] = X1; pw[2] = Y0; pw[3] = Y1;
        const short8 paf = __builtin_bit_cast(short8, pw);
        acc = __builtin_amdgcn_mfma_f32_32x32x16_bf16(paf, vf[ks], acc, 0, 0, 0);
    }

    if (q31 < 16) {
        #pragma unroll
        for (int rp = 0; rp < 8; ++rp) {
            const int r = rp * 2;
            const int a = (r & 3) + 8 * (r >> 2) + 4 * hi;
            unsigned pk;
            asm("v_cvt_pk_bf16_f32 %0, %1, %2" : "=v"(pk) : "v"(acc[r]), "v"(acc[r+1]));
            *(unsigned*)((char*)c_s + q31*264 + (w*32 + a)*2) = pk;
        }
    }
    __syncthreads();
    *(short8*)(Cc + tb + t*8) = *(const short8*)((char*)c_s + (t >> 4)*264 + (t & 15)*16);
}

extern "C" void kernel_launch(void* const* d_in, const int* in_sizes, int n_in,
                              void* d_out, int out_size, void* d_ws, size_t ws_size,
                              hipStream_t stream) {
    (void)in_sizes; (void)n_in; (void)out_size; (void)ws_size;
    const float* q    = (const float*)d_in[0];
    const float* k    = (const float*)d_in[1];
    const float* v    = (const float*)d_in[2];
    const float* nq_a = (const float*)d_in[3];
    const float* nq_b = (const float*)d_in[4];
    const float* nk_a = (const float*)d_in[5];
    const float* nk_b = (const float*)d_in[6];
    const float* nv_a = (const float*)d_in[7];
    const float* nv_b = (const float*)d_in[8];
    const float* n2_a = (const float*)d_in[9];
    const float* n2_b = (const float*)d_in[10];
    const float* Wq   = (const float*)d_in[11];
    const float* bq   = (const float*)d_in[12];
    const float* Wk   = (const float*)d_in[13];
    const float* bk   = (const float*)d_in[14];
    const float* Wv   = (const float*)d_in[15];
    const float* bv   = (const float*)d_in[16];
    const float* Wo   = (const float*)d_in[17];
    const float* bo   = (const float*)d_in[18];
    const float* W1   = (const float*)d_in[19];
    const float* b1   = (const float*)d_in[20];
    const float* W2   = (const float*)d_in[21];
    const float* b2   = (const float*)d_in[22];

    char* ws = (char*)d_ws;
    const size_t MB = 1024 * 1024;
    unsigned short* buf0 = (unsigned short*)(ws);
    unsigned short* QtB  = (unsigned short*)(ws + 32*MB);
    unsigned short* KtB  = (unsigned short*)(ws + 64*MB);
    unsigned short* VpB  = (unsigned short*)(ws + 96*MB);
    unsigned short* Wqt  = (unsigned short*)(ws + 128*MB);
    unsigned short* Wkt  = (unsigned short*)(ws + 136*MB);
    unsigned short* Wvt  = (unsigned short*)(ws + 144*MB);
    unsigned short* Wot  = (unsigned short*)(ws + 152*MB);
    unsigned short* W1t  = (unsigned short*)(ws + 160*MB);
    unsigned short* W2t  = (unsigned short*)(ws + 168*MB);
    unsigned short* x2   = QtB;   // after Q consumed
    unsigned short* h1   = KtB;   // after K consumed
    unsigned short* xb   = VpB;   // bf16 residual stream, after V consumed
    float* x = (float*)d_out;     // final f32 output

    const float isq = 0.088388347648318447f; // 1/sqrt(128), folded into Wq/bq

    dim3 b256(256);
    dim3 gT6(DM / 32, DM / 32, 6);
    wtrans6<<<gT6, b256, 0, stream>>>(Wq, Wk, Wv, Wo, W1, W2,
                                      Wqt, Wkt, Wvt, Wot, W1t, W2t, isq);

    dim3 gN(NTOK);
    dim3 gG(256);
    dim3 b512(512);

    norm_rows<<<gN, b256, 0, stream>>>(q, nq_a, nq_b, buf0);
    gemm256<0><<<gG, b512, 0, stream>>>(buf0, Wqt, bq, nullptr, nullptr, nullptr, QtB, 1, isq);
    norm_rows<<<gN, b256, 0, stream>>>(k, nk_a, nk_b, buf0);
    gemm256<0><<<gG, b512, 0, stream>>>(buf0, Wkt, bk, nullptr, nullptr, nullptr, KtB, 1, 1.0f);
    norm_rows<<<gN, b256, 0, stream>>>(v, nv_a, nv_b, buf0);
    gemm256<0><<<gG, b512, 0, stream>>>(buf0, Wvt, bv, nullptr, nullptr, nullptr, VpB, 0, 1.0f);
    attn_tok<<<gN, b256, 0, stream>>>(QtB, KtB, VpB, buf0);
    gemm256<3><<<gG, b512, 0, stream>>>(buf0, Wot, bo, v, nullptr, nullptr, xb, 0, 1.0f);
    norm_rows_bf16<<<gN, b256, 0, stream>>>(xb, n2_a, n2_b, x2);
    gemm256<1><<<gG, b512, 0, stream>>>(x2, W1t, b1, nullptr, nullptr, nullptr, h1, 0, 1.0f);
    gemm256<4><<<gG, b512, 0, stream>>>(h1, W2t, b2, nullptr, xb, x, nullptr, 0, 1.0f);
}

// Round 6
// 554.620 us; speedup vs baseline: 1.6537x; 1.0452x over previous
//
#include <hip/hip_runtime.h>
#include <hip/hip_bf16.h>

#define DM 2048
#define NTOK 8192
#define EPS 1e-6f

typedef __attribute__((ext_vector_type(8))) short short8;
typedef __attribute__((ext_vector_type(4))) short short4v;
typedef __attribute__((ext_vector_type(4))) float f32x4;
typedef __attribute__((ext_vector_type(16))) float f32x16;
typedef __attribute__((ext_vector_type(4))) unsigned int u32x4;

typedef const __attribute__((address_space(1))) void gvoid;
typedef __attribute__((address_space(3))) void lvoid;

static __device__ __forceinline__ unsigned short f2bf(float f) {
    unsigned u = __builtin_bit_cast(unsigned, f);
    unsigned r = u + 0x7FFFu + ((u >> 16) & 1u);
    return (unsigned short)(r >> 16);
}
static __device__ __forceinline__ float bf2f(unsigned short h) {
    return __builtin_bit_cast(float, (unsigned)h << 16);
}

// ---------------- row norm (f32 in): alpha*(x-mu)/(std+eps)+beta, std ddof=1 -> bf16 out
__global__ __launch_bounds__(256) void norm_rows(
        const float* __restrict__ in, const float* __restrict__ alpha,
        const float* __restrict__ beta, unsigned short* __restrict__ out) {
    const int row = blockIdx.x;
    const int t = threadIdx.x;
    const float* x = in + (size_t)row * DM + t * 8;
    float4 v0 = *(const float4*)(x);
    float4 v1 = *(const float4*)(x + 4);
    float s = (v0.x + v0.y) + (v0.z + v0.w) + (v1.x + v1.y) + (v1.z + v1.w);
    float ss = v0.x*v0.x + v0.y*v0.y + v0.z*v0.z + v0.w*v0.w
             + v1.x*v1.x + v1.y*v1.y + v1.z*v1.z + v1.w*v1.w;
    #pragma unroll
    for (int m = 1; m < 64; m <<= 1) {
        s  += __shfl_xor(s, m);
        ss += __shfl_xor(ss, m);
    }
    __shared__ float red[8];
    const int wv = t >> 6, ln = t & 63;
    if (ln == 0) { red[wv] = s; red[4 + wv] = ss; }
    __syncthreads();
    s  = (red[0] + red[1]) + (red[2] + red[3]);
    ss = (red[4] + red[5]) + (red[6] + red[7]);
    const float mu = s * (1.0f / DM);
    float var = (ss - s * mu) * (1.0f / (DM - 1));
    var = fmaxf(var, 0.0f);
    const float scale = 1.0f / (sqrtf(var) + EPS);
    float4 a0 = *(const float4*)(alpha + t*8);
    float4 a1 = *(const float4*)(alpha + t*8 + 4);
    float4 b0 = *(const float4*)(beta + t*8);
    float4 b1 = *(const float4*)(beta + t*8 + 4);
    short8 o;
    o[0] = (short)f2bf(a0.x * (v0.x - mu) * scale + b0.x);
    o[1] = (short)f2bf(a0.y * (v0.y - mu) * scale + b0.y);
    o[2] = (short)f2bf(a0.z * (v0.z - mu) * scale + b0.z);
    o[3] = (short)f2bf(a0.w * (v0.w - mu) * scale + b0.w);
    o[4] = (short)f2bf(a1.x * (v1.x - mu) * scale + b1.x);
    o[5] = (short)f2bf(a1.y * (v1.y - mu) * scale + b1.y);
    o[6] = (short)f2bf(a1.z * (v1.z - mu) * scale + b1.z);
    o[7] = (short)f2bf(a1.w * (v1.w - mu) * scale + b1.w);
    *(short8*)(out + (size_t)row * DM + t * 8) = o;
}

// ---------------- row norm (bf16 in) -> bf16 out
__global__ __launch_bounds__(256) void norm_rows_bf16(
        const unsigned short* __restrict__ in, const float* __restrict__ alpha,
        const float* __restrict__ beta, unsigned short* __restrict__ out) {
    const int row = blockIdx.x;
    const int t = threadIdx.x;
    short8 rv = *(const short8*)(in + (size_t)row * DM + t * 8);
    float xv[8];
    #pragma unroll
    for (int j = 0; j < 8; ++j) xv[j] = bf2f((unsigned short)rv[j]);
    float s = 0.f, ss = 0.f;
    #pragma unroll
    for (int j = 0; j < 8; ++j) { s += xv[j]; ss += xv[j]*xv[j]; }
    #pragma unroll
    for (int m = 1; m < 64; m <<= 1) {
        s  += __shfl_xor(s, m);
        ss += __shfl_xor(ss, m);
    }
    __shared__ float red[8];
    const int wv = t >> 6, ln = t & 63;
    if (ln == 0) { red[wv] = s; red[4 + wv] = ss; }
    __syncthreads();
    s  = (red[0] + red[1]) + (red[2] + red[3]);
    ss = (red[4] + red[5]) + (red[6] + red[7]);
    const float mu = s * (1.0f / DM);
    float var = (ss - s * mu) * (1.0f / (DM - 1));
    var = fmaxf(var, 0.0f);
    const float scale = 1.0f / (sqrtf(var) + EPS);
    short8 o;
    #pragma unroll
    for (int j = 0; j < 8; ++j) {
        const float av = alpha[t*8 + j], bv = beta[t*8 + j];
        o[j] = (short)f2bf(av * (xv[j] - mu) * scale + bv);
    }
    *(short8*)(out + (size_t)row * DM + t * 8) = o;
}

// ---------------- fused weight transpose+cast+scale for all 6 weights (z picks matrix)
__global__ __launch_bounds__(256) void wtrans6(
        const float* __restrict__ Wq, const float* __restrict__ Wk,
        const float* __restrict__ Wv, const float* __restrict__ Wo,
        const float* __restrict__ W1, const float* __restrict__ W2,
        unsigned short* __restrict__ Tq, unsigned short* __restrict__ Tk,
        unsigned short* __restrict__ Tv, unsigned short* __restrict__ To,
        unsigned short* __restrict__ T1, unsigned short* __restrict__ T2,
        float isq) {
    __shared__ float tile[32][33];
    const int z = blockIdx.z;
    const float* W = z==0?Wq: z==1?Wk: z==2?Wv: z==3?Wo: z==4?W1: W2;
    unsigned short* Wt = z==0?Tq: z==1?Tk: z==2?Tv: z==3?To: z==4?T1: T2;
    const int perm = (z < 2) ? 1 : 0;
    const float ws = (z == 0) ? isq : 1.0f;
    const int bc = blockIdx.x * 32, bk = blockIdx.y * 32;
    const int t = threadIdx.x;
    const int tc = t & 31, tr = t >> 5;
    #pragma unroll
    for (int i = 0; i < 4; ++i)
        tile[tr + i*8][tc] = W[(size_t)(bk + tr + i*8) * DM + bc + tc];
    __syncthreads();
    #pragma unroll
    for (int i = 0; i < 4; ++i) {
        const int c = bc + tr + i*8;
        const int pc = perm ? ((c & 127) * 16 + (c >> 7)) : c;
        Wt[(size_t)pc * DM + bk + tc] = f2bf(tile[tc][tr + i*8] * ws);
    }
}

// ---------------- 256x256x64 8-phase GEMM, 1 half-tile stage per phase, vmcnt(4) counted
// Quadrant order (0,0),(1,0),(0,1),(1,1); both A halves live in regs (af[8][2]).
// EPI 0: bf16+bias. 1: bf16+bias+relu. 3: bf16+bias+f32 resid. 4: f32+bias+bf16 resid.
#define BARRIER __builtin_amdgcn_s_barrier()
#define WAIT_LGKM0 asm volatile("s_waitcnt lgkmcnt(0)" ::: "memory")
#define VMCNT(n) asm volatile("s_waitcnt vmcnt(" #n ")" ::: "memory")

template<int EPI>
__global__ __launch_bounds__(512, 2) void gemm256(
        const unsigned short* __restrict__ A, const unsigned short* __restrict__ Bt,
        const float* __restrict__ bias, const float* __restrict__ residF,
        const unsigned short* __restrict__ residB,
        float* __restrict__ outF, unsigned short* __restrict__ outB, int biasPerm,
        float bscale) {
    __shared__ __align__(16) char lds[131072];
    char* ldsA = lds;
    char* ldsB = lds + 65536;

    const int t = threadIdx.x, l = t & 63, w = t >> 6;
    const int wm = w >> 2, wn = w & 3;

    // T1: each XCD owns a 4M x 8N tile region
    const int b = blockIdx.x;
    const int xcd = b & 7;
    const int j = b >> 3;
    const int m0 = (xcd * 4 + (j & 3)) * 256;
    const int n0 = (j >> 2) * 256;

    const int rS = t >> 3;
    const int cS = ((t & 7) ^ (rS & 7)) * 8;
    const unsigned short* aSt = A  + (size_t)(m0 + rS) * 2048 + cS;
    const unsigned short* bSt = Bt + (size_t)(n0 + rS) * 2048 + cS;
    const int ldsStW = w * 1024;

    const int aRd = wm * 16384 + (l & 15) * 128;
    const int bRd = (wn >> 1) * 16384 + (wn & 1) * 8192 + (l & 15) * 128;
    const int ch0 = (((l >> 4) + 0) ^ (l & 7)) * 16;
    const int ch1 = (((l >> 4) + 4) ^ (l & 7)) * 16;

    short8 af[8][2], bf[4][2];
    f32x4 acc[8][4] = {};

#define STG_A(buf, h, kt) do { \
    __builtin_amdgcn_global_load_lds((gvoid*)(aSt + (size_t)((h)*128)*2048 + (kt)*64), \
        (lvoid*)(ldsA + (buf)*32768 + (h)*16384 + ldsStW), 16, 0, 0); \
    __builtin_amdgcn_global_load_lds((gvoid*)(aSt + (size_t)((h)*128+64)*2048 + (kt)*64), \
        (lvoid*)(ldsA + (buf)*32768 + (h)*16384 + 8192 + ldsStW), 16, 0, 0); \
} while(0)
#define STG_B(buf, h, kt) do { \
    __builtin_amdgcn_global_load_lds((gvoid*)(bSt + (size_t)((h)*128)*2048 + (kt)*64), \
        (lvoid*)(ldsB + (buf)*32768 + (h)*16384 + ldsStW), 16, 0, 0); \
    __builtin_amdgcn_global_load_lds((gvoid*)(bSt + (size_t)((h)*128+64)*2048 + (kt)*64), \
        (lvoid*)(ldsB + (buf)*32768 + (h)*16384 + 8192 + ldsStW), 16, 0, 0); \
} while(0)
#define RD_A(buf, mh) do { \
    _Pragma("unroll") for (int ml = 0; ml < 4; ++ml) { \
        af[(mh)*4+ml][0] = *(const short8*)(ldsA + (buf)*32768 + aRd + ((mh)*4+ml)*2048 + ch0); \
        af[(mh)*4+ml][1] = *(const short8*)(ldsA + (buf)*32768 + aRd + ((mh)*4+ml)*2048 + ch1); \
    } } while(0)
#define RD_B(buf, nh) do { \
    _Pragma("unroll") for (int nl = 0; nl < 2; ++nl) { \
        bf[(nh)*2+nl][0] = *(const short8*)(ldsB + (buf)*32768 + bRd + ((nh)*2+nl)*2048 + ch0); \
        bf[(nh)*2+nl][1] = *(const short8*)(ldsB + (buf)*32768 + bRd + ((nh)*2+nl)*2048 + ch1); \
    } } while(0)
#define MM_Q(mh, nh) do { \
    __builtin_amdgcn_s_setprio(1); \
    _Pragma("unroll") for (int ml = 0; ml < 4; ++ml) \
    _Pragma("unroll") for (int nl = 0; nl < 2; ++nl) { \
        acc[(mh)*4+ml][(nh)*2+nl] = __builtin_amdgcn_mfma_f32_16x16x32_bf16( \
            af[(mh)*4+ml][0], bf[(nh)*2+nl][0], acc[(mh)*4+ml][(nh)*2+nl], 0, 0, 0); \
        acc[(mh)*4+ml][(nh)*2+nl] = __builtin_amdgcn_mfma_f32_16x16x32_bf16( \
            af[(mh)*4+ml][1], bf[(nh)*2+nl][1], acc[(mh)*4+ml][(nh)*2+nl], 0, 0, 0); \
    } \
    __builtin_amdgcn_s_setprio(0); \
} while(0)

    // prologue: kt0 A+B, kt1 A; retire kt0 (oldest 8)
    STG_A(0, 0, 0); STG_A(0, 1, 0);
    STG_B(0, 0, 0); STG_B(0, 1, 0);
    STG_A(1, 0, 1); STG_A(1, 1, 1);
    VMCNT(4);
    BARRIER;

    #pragma unroll 1
    for (int i = 0; i < 16; ++i) {
        const int kt1 = 2*i + 1, k2 = 2*i + 2, k3 = 2*i + 3;
        const bool more = (i < 15);
        // P1: quad(0,0) of kt0; stage B(kt1) h0
        RD_A(0, 0); RD_B(0, 0);
        STG_B(1, 0, kt1);
        BARRIER; WAIT_LGKM0;
        MM_Q(0, 0);
        BARRIER;
        // P2: quad(1,0); stage B(kt1) h1  [buf0-A fully read after this phase]
        RD_A(0, 1);
        STG_B(1, 1, kt1);
        BARRIER; WAIT_LGKM0;
        MM_Q(1, 0);
        BARRIER;
        // P3: quad(0,1); stage A(k2) h0 into freed buf0-A
        RD_B(0, 1);
        if (more) STG_A(0, 0, k2);
        BARRIER; WAIT_LGKM0;
        MM_Q(0, 1);
        BARRIER;
        // P4: quad(1,1); stage A(k2) h1; vmcnt(4) retires kt1's A+B
        if (more) { STG_A(0, 1, k2); VMCNT(4); } else { VMCNT(0); }
        BARRIER;
        MM_Q(1, 1);
        BARRIER;
        // P5: quad(0,0) of kt1; stage B(k2) h0 into freed buf0-B
        RD_A(1, 0); RD_B(1, 0);
        if (more) STG_B(0, 0, k2);
        BARRIER; WAIT_LGKM0;
        MM_Q(0, 0);
        BARRIER;
        // P6: quad(1,0); stage B(k2) h1
        RD_A(1, 1);
        if (more) STG_B(0, 1, k2);
        BARRIER; WAIT_LGKM0;
        MM_Q(1, 0);
        BARRIER;
        // P7: quad(0,1); stage A(k3) h0 into freed buf1-A
        RD_B(1, 1);
        if (more) STG_A(1, 0, k3);
        BARRIER; WAIT_LGKM0;
        MM_Q(0, 1);
        BARRIER;
        // P8: quad(1,1); stage A(k3) h1; vmcnt(4) retires k2's A+B
        if (more) { STG_A(1, 1, k3); VMCNT(4); }
        BARRIER;
        MM_Q(1, 1);
        BARRIER;
    }

    // ---- epilogue: stage bf16(acc+bias[+relu]) in LDS, coalesced full-row stores ----
    unsigned short* cs = (unsigned short*)lds;   // [128][260] padded
    #pragma unroll 1
    for (int pass = 0; pass < 2; ++pass) {
        BARRIER;
        if (wm == pass) {
            #pragma unroll
            for (int ni = 0; ni < 4; ++ni) {
                const int col = wn*64 + ni*16 + (l & 15);
                const int gcol = n0 + col;
                const int cb = biasPerm ? ((gcol >> 4) + (gcol & 15) * 128) : gcol;
                const float bvv = bias[cb] * bscale;
                #pragma unroll
                for (int mi = 0; mi < 8; ++mi) {
                    #pragma unroll
                    for (int r = 0; r < 4; ++r) {
                        const int row = mi*16 + (l >> 4)*4 + r;
                        float vv = acc[mi][ni][r] + bvv;
                        if (EPI == 1) vv = fmaxf(vv, 0.0f);
                        cs[row*260 + col] = f2bf(vv);
                    }
                }
            }
        }
        BARRIER;
        #pragma unroll
        for (int s = 0; s < 8; ++s) {
            const int row = (t >> 5) + s*16;
            const int seg = t & 31;
            short8 pk = *(const short8*)(cs + row*260 + seg*8);
            const int grow = m0 + pass*128 + row;
            const size_t gb = (size_t)grow * 2048 + n0 + seg*8;
            if (EPI == 3) {
                float4 r0 = *(const float4*)(residF + gb);
                float4 r1 = *(const float4*)(residF + gb + 4);
                short8 o;
                o[0] = (short)f2bf(bf2f((unsigned short)pk[0]) + r0.x);
                o[1] = (short)f2bf(bf2f((unsigned short)pk[1]) + r0.y);
                o[2] = (short)f2bf(bf2f((unsigned short)pk[2]) + r0.z);
                o[3] = (short)f2bf(bf2f((unsigned short)pk[3]) + r0.w);
                o[4] = (short)f2bf(bf2f((unsigned short)pk[4]) + r1.x);
                o[5] = (short)f2bf(bf2f((unsigned short)pk[5]) + r1.y);
                o[6] = (short)f2bf(bf2f((unsigned short)pk[6]) + r1.z);
                o[7] = (short)f2bf(bf2f((unsigned short)pk[7]) + r1.w);
                *(short8*)(outB + gb) = o;
            } else if (EPI == 4) {
                short8 rb = *(const short8*)(residB + gb);
                float4 o0, o1;
                o0.x = bf2f((unsigned short)pk[0]) + bf2f((unsigned short)rb[0]);
                o0.y = bf2f((unsigned short)pk[1]) + bf2f((unsigned short)rb[1]);
                o0.z = bf2f((unsigned short)pk[2]) + bf2f((unsigned short)rb[2]);
                o0.w = bf2f((unsigned short)pk[3]) + bf2f((unsigned short)rb[3]);
                o1.x = bf2f((unsigned short)pk[4]) + bf2f((unsigned short)rb[4]);
                o1.y = bf2f((unsigned short)pk[5]) + bf2f((unsigned short)rb[5]);
                o1.z = bf2f((unsigned short)pk[6]) + bf2f((unsigned short)rb[6]);
                o1.w = bf2f((unsigned short)pk[7]) + bf2f((unsigned short)rb[7]);
                *(float4*)(outF + gb) = o0;
                *(float4*)(outF + gb + 4) = o1;
            } else {
                *(short8*)(outB + gb) = pk;
            }
        }
    }
#undef STG_A
#undef STG_B
#undef RD_A
#undef RD_B
#undef MM_Q
}

// ---------------- per-token attention, fully in-register (swapped QK^T + cvt_pk/permlane)
__global__ __launch_bounds__(256) void attn_tok(
        const unsigned short* __restrict__ Qt, const unsigned short* __restrict__ Kt,
        const unsigned short* __restrict__ Vp, unsigned short* __restrict__ Cc) {
    const int n = blockIdx.x;
    const int t = threadIdx.x, w = t >> 6, l = t & 63;
    const int q31 = l & 31, hi = l >> 5;
    __shared__ __align__(16) unsigned short c_s[16 * 132];

    const size_t tb = (size_t)n * DM;
    const short8 qf = *(const short8*)(Qt + tb + (w*32 + q31)*16 + hi*8);
    short8 kf[4];
    #pragma unroll
    for (int bt = 0; bt < 4; ++bt)
        kf[bt] = *(const short8*)(Kt + tb + (bt*32 + q31)*16 + hi*8);
    short8 vf[8];
    #pragma unroll
    for (int ks = 0; ks < 8; ++ks)
        vf[ks] = *(const short8*)(Vp + tb + (q31 & 15)*128 + ks*16 + hi*8);

    const f32x16 z = {};
    f32x16 sc[4];
    #pragma unroll
    for (int bt = 0; bt < 4; ++bt)
        sc[bt] = __builtin_amdgcn_mfma_f32_32x32x16_bf16(kf[bt], qf, z, 0, 0, 0);

    float m0 = sc[0][0], m1 = sc[1][0], m2 = sc[2][0], m3 = sc[3][0];
    #pragma unroll
    for (int r = 1; r < 16; ++r) {
        m0 = fmaxf(m0, sc[0][r]); m1 = fmaxf(m1, sc[1][r]);
        m2 = fmaxf(m2, sc[2][r]); m3 = fmaxf(m3, sc[3][r]);
    }
    float mx = fmaxf(fmaxf(m0, m1), fmaxf(m2, m3));
    { float a2 = mx, b2 = mx;
      asm volatile("v_permlane32_swap_b32 %0, %1" : "+v"(a2), "+v"(b2));
      mx = fmaxf(a2, b2); }

    float p[4][16];
    float s0 = 0.f, s1 = 0.f, s2 = 0.f, s3 = 0.f;
    #pragma unroll
    for (int r = 0; r < 16; ++r) {
        p[0][r] = __expf(sc[0][r] - mx); s0 += p[0][r];
        p[1][r] = __expf(sc[1][r] - mx); s1 += p[1][r];
        p[2][r] = __expf(sc[2][r] - mx); s2 += p[2][r];
        p[3][r] = __expf(sc[3][r] - mx); s3 += p[3][r];
    }
    float sm = (s0 + s1) + (s2 + s3);
    { float a2 = sm, b2 = sm;
      asm volatile("v_permlane32_swap_b32 %0, %1" : "+v"(a2), "+v"(b2));
      sm = a2 + b2; }
    const float inv = __builtin_amdgcn_rcpf(sm);
    #pragma unroll
    for (int bt = 0; bt < 4; ++bt)
        #pragma unroll
        for (int r = 0; r < 16; ++r)
            p[bt][r] *= inv;

    f32x16 acc = {};
    #pragma unroll
    for (int ks = 0; ks < 8; ++ks) {
        const int bt = ks >> 1, r0 = (ks & 1) * 8;
        unsigned X0, Y0, X1, Y1;
        asm("v_cvt_pk_bf16_f32 %0, %1, %2" : "=v"(X0) : "v"(p[bt][r0+0]), "v"(p[bt][r0+1]));
        asm("v_cvt_pk_bf16_f32 %0, %1, %2" : "=v"(Y0) : "v"(p[bt][r0+4]), "v"(p[bt][r0+5]));
        asm("v_cvt_pk_bf16_f32 %0, %1, %2" : "=v"(X1) : "v"(p[bt][r0+2]), "v"(p[bt][r0+3]));
        asm("v_cvt_pk_bf16_f32 %0, %1, %2" : "=v"(Y1) : "v"(p[bt][r0+6]), "v"(p[bt][r0+7]));
        asm volatile("v_permlane32_swap_b32 %0, %1" : "+v"(X0), "+v"(Y0));
        asm volatile("v_permlane32_swap_b32 %0, %1" : "+v"(X1), "+v"(Y1));
        u32x4 pw; pw[0] = X0; pw[1] = X1; pw[2] = Y0; pw[3] = Y1;
        const short8 paf = __builtin_bit_cast(short8, pw);
        acc = __builtin_amdgcn_mfma_f32_32x32x16_bf16(paf, vf[ks], acc, 0, 0, 0);
    }

    if (q31 < 16) {
        #pragma unroll
        for (int rp = 0; rp < 8; ++rp) {
            const int r = rp * 2;
            const int a = (r & 3) + 8 * (r >> 2) + 4 * hi;
            unsigned pk;
            asm("v_cvt_pk_bf16_f32 %0, %1, %2" : "=v"(pk) : "v"(acc[r]), "v"(acc[r+1]));
            *(unsigned*)((char*)c_s + q31*264 + (w*32 + a)*2) = pk;
        }
    }
    __syncthreads();
    *(short8*)(Cc + tb + t*8) = *(const short8*)((char*)c_s + (t >> 4)*264 + (t & 15)*16);
}

extern "C" void kernel_launch(void* const* d_in, const int* in_sizes, int n_in,
                              void* d_out, int out_size, void* d_ws, size_t ws_size,
                              hipStream_t stream) {
    (void)in_sizes; (void)n_in; (void)out_size; (void)ws_size;
    const float* q    = (const float*)d_in[0];
    const float* k    = (const float*)d_in[1];
    const float* v    = (const float*)d_in[2];
    const float* nq_a = (const float*)d_in[3];
    const float* nq_b = (const float*)d_in[4];
    const float* nk_a = (const float*)d_in[5];
    const float* nk_b = (const float*)d_in[6];
    const float* nv_a = (const float*)d_in[7];
    const float* nv_b = (const float*)d_in[8];
    const float* n2_a = (const float*)d_in[9];
    const float* n2_b = (const float*)d_in[10];
    const float* Wq   = (const float*)d_in[11];
    const float* bq   = (const float*)d_in[12];
    const float* Wk   = (const float*)d_in[13];
    const float* bk   = (const float*)d_in[14];
    const float* Wv   = (const float*)d_in[15];
    const float* bv   = (const float*)d_in[16];
    const float* Wo   = (const float*)d_in[17];
    const float* bo   = (const float*)d_in[18];
    const float* W1   = (const float*)d_in[19];
    const float* b1   = (const float*)d_in[20];
    const float* W2   = (const float*)d_in[21];
    const float* b2   = (const float*)d_in[22];

    char* ws = (char*)d_ws;
    const size_t MB = 1024 * 1024;
    unsigned short* buf0 = (unsigned short*)(ws);
    unsigned short* QtB  = (unsigned short*)(ws + 32*MB);
    unsigned short* KtB  = (unsigned short*)(ws + 64*MB);
    unsigned short* VpB  = (unsigned short*)(ws + 96*MB);
    unsigned short* Wqt  = (unsigned short*)(ws + 128*MB);
    unsigned short* Wkt  = (unsigned short*)(ws + 136*MB);
    unsigned short* Wvt  = (unsigned short*)(ws + 144*MB);
    unsigned short* Wot  = (unsigned short*)(ws + 152*MB);
    unsigned short* W1t  = (unsigned short*)(ws + 160*MB);
    unsigned short* W2t  = (unsigned short*)(ws + 168*MB);
    unsigned short* x2   = QtB;   // after Q consumed
    unsigned short* h1   = KtB;   // after K consumed
    unsigned short* xb   = VpB;   // bf16 residual stream, after V consumed
    float* x = (float*)d_out;     // final f32 output

    const float isq = 0.088388347648318447f; // 1/sqrt(128), folded into Wq/bq

    dim3 b256(256);
    dim3 gT6(DM / 32, DM / 32, 6);
    wtrans6<<<gT6, b256, 0, stream>>>(Wq, Wk, Wv, Wo, W1, W2,
                                      Wqt, Wkt, Wvt, Wot, W1t, W2t, isq);

    dim3 gN(NTOK);
    dim3 gG(256);
    dim3 b512(512);

    norm_rows<<<gN, b256, 0, stream>>>(q, nq_a, nq_b, buf0);
    gemm256<0><<<gG, b512, 0, stream>>>(buf0, Wqt, bq, nullptr, nullptr, nullptr, QtB, 1, isq);
    norm_rows<<<gN, b256, 0, stream>>>(k, nk_a, nk_b, buf0);
    gemm256<0><<<gG, b512, 0, stream>>>(buf0, Wkt, bk, nullptr, nullptr, nullptr, KtB, 1, 1.0f);
    norm_rows<<<gN, b256, 0, stream>>>(v, nv_a, nv_b, buf0);
    gemm256<0><<<gG, b512, 0, stream>>>(buf0, Wvt, bv, nullptr, nullptr, nullptr, VpB, 0, 1.0f);
    attn_tok<<<gN, b256, 0, stream>>>(QtB, KtB, VpB, buf0);
    gemm256<3><<<gG, b512, 0, stream>>>(buf0, Wot, bo, v, nullptr, nullptr, xb, 0, 1.0f);
    norm_rows_bf16<<<gN, b256, 0, stream>>>(xb, n2_a, n2_b, x2);
    gemm256<1><<<gG, b512, 0, stream>>>(x2, W1t, b1, nullptr, nullptr, nullptr, h1, 0, 1.0f);
    gemm256<4><<<gG, b512, 0, stream>>>(h1, W2t, b2, nullptr, xb, x, nullptr, 0, 1.0f);
}